// Round 1
// 4910.267 us; speedup vs baseline: 1.7637x; 1.7637x over previous
//
#include <hip/hip_runtime.h>

typedef unsigned short u16;
typedef unsigned int u32;
typedef __attribute__((ext_vector_type(8))) short bf16x8;
typedef __attribute__((ext_vector_type(4))) float f32x4;

#define CC_    256         // channels
#define NHD_   8           // heads
#define NT_    64          // tokens per window
#define HD_    32          // head dim
#define HID_   1024        // mlp hidden
#define CPBH_  512         // cpb hidden
#define BW_    2048        // total windows = 32 * 64
#define TOK_   131072      // total tokens
#define SHIFT_ 4

// region id (0..8) in the shifted canvas for mask construction
__device__ __forceinline__ int region9(int ph, int pw) {
  return (ph < 56 ? 0 : (ph < 60 ? 3 : 6)) + (pw < 56 ? 0 : (pw < 60 ? 1 : 2));
}
__device__ __forceinline__ float dot32(const float* qr, const float* krow) {
  float d0 = 0.f, d1 = 0.f, d2 = 0.f, d3 = 0.f;
#pragma unroll
  for (int d = 0; d < HD_; d += 4) {
    float4 kk = *reinterpret_cast<const float4*>(krow + d);
    d0 += qr[d] * kk.x; d1 += qr[d + 1] * kk.y;
    d2 += qr[d + 2] * kk.z; d3 += qr[d + 3] * kk.w;
  }
  return (d0 + d1) + (d2 + d3);
}

// fp32 -> bf16 round-to-nearest-even (finite values only)
__device__ __forceinline__ u16 f2bf(float f) {
  u32 u = __builtin_bit_cast(u32, f);
  u = (u + 0x7FFFu + ((u >> 16) & 1u)) >> 16;
  return (u16)u;
}

// ---------------- kernel 1: CPB MLP -> bias_table[225][8] ----------------
__global__ void cpb_kernel(const float* __restrict__ w1, const float* __restrict__ b1,
                           const float* __restrict__ w2, float* __restrict__ bias_table) {
  __shared__ float hid[CPBH_];
  int p = blockIdx.x;        // 0..224
  int k = threadIdx.x;       // 0..511
  int hi = p / 15, wi = p % 15;
  float a0 = (float)(hi - 7) / 7.0f * 8.0f;
  float a1 = (float)(wi - 7) / 7.0f * 8.0f;
  float t0 = (a0 == 0.0f) ? 0.0f : copysignf(log2f(fabsf(a0) + 1.0f) / 3.0f, a0);
  float t1 = (a1 == 0.0f) ? 0.0f : copysignf(log2f(fabsf(a1) + 1.0f) / 3.0f, a1);
  float h = t0 * w1[2 * k] + t1 * w1[2 * k + 1] + b1[k];
  hid[k] = fmaxf(h, 0.0f);
  __syncthreads();
  if (k < NHD_) {
    float s = 0.0f;
    for (int j = 0; j < CPBH_; j++) s += hid[j] * w2[k * CPBH_ + j];
    bias_table[p * NHD_ + k] = s;
  }
}

// ---------------- kernel 2: gather + sigmoid -> rpb[8][64][64] ----------------
__global__ void rpb_kernel(const float* __restrict__ bias_table, float* __restrict__ rpb) {
  int h = blockIdx.x >> 6;   // grid 512
  int i = blockIdx.x & 63;
  int j = threadIdx.x;       // 64
  int dih = (i >> 3) - (j >> 3) + 7;
  int diw = (i & 7) - (j & 7) + 7;
  float v = bias_table[(dih * 15 + diw) * NHD_ + h];
  rpb[(((h << 6) + i) << 6) + j] = 16.0f / (1.0f + expf(-v));
}

// ---------------- weight fp32 -> bf16 conversion ----------------
__global__ void convw_kernel(const float* __restrict__ w, u16* __restrict__ o, int n) {
  int i = blockIdx.x * 256 + threadIdx.x;
  if (i < n) o[i] = f2bf(w[i]);
}

// ---------------- kernel 3: shifted-window gather + QKV GEMM (chunk of windows) ----------------
__global__ __launch_bounds__(256) void qkv_kernel(
    const float* __restrict__ x, const float* __restrict__ qkvw,
    const float* __restrict__ qb, const float* __restrict__ vb,
    float* __restrict__ qo, float* __restrict__ ko, float* __restrict__ vo, int w0) {
  __shared__ float xs[8][CC_];
  int blk = blockIdx.x;          // nw*8
  int wl = blk >> 3;             // chunk-local window
  int w = w0 + wl;               // global window
  int n0 = (blk & 7) << 3;       // first token in window
  int tid = threadIdx.x;
  int b = w >> 6, win = w & 63;
  int wh = win >> 3, ww = win & 7;
  for (int t = 0; t < 8; t++) {
    int n = n0 + t;
    int sh = wh * 8 + (n >> 3), sw = ww * 8 + (n & 7);
    int hh = (sh + SHIFT_) & 63, wc = (sw + SHIFT_) & 63;
    size_t src = ((size_t)((b << 12) + (hh << 6) + wc)) * CC_;
    xs[t][tid] = x[src + tid];
  }
  __syncthreads();
  int oc = tid;
  float accq[8], acck[8], accv[8];
#pragma unroll
  for (int t = 0; t < 8; t++) { accq[t] = 0.f; acck[t] = 0.f; accv[t] = 0.f; }
  const float* wq = qkvw + (size_t)oc * CC_;
  const float* wk = qkvw + (size_t)(oc + CC_) * CC_;
  const float* wv = qkvw + (size_t)(oc + 2 * CC_) * CC_;
  for (int c0 = 0; c0 < CC_; c0 += 4) {
    float4 fq = *reinterpret_cast<const float4*>(wq + c0);
    float4 fk = *reinterpret_cast<const float4*>(wk + c0);
    float4 fv = *reinterpret_cast<const float4*>(wv + c0);
#pragma unroll
    for (int t = 0; t < 8; t++) {
      float4 xt = *reinterpret_cast<const float4*>(&xs[t][c0]);
      accq[t] += xt.x * fq.x + xt.y * fq.y + xt.z * fq.z + xt.w * fq.w;
      acck[t] += xt.x * fk.x + xt.y * fk.y + xt.z * fk.z + xt.w * fk.w;
      accv[t] += xt.x * fv.x + xt.y * fv.y + xt.z * fv.z + xt.w * fv.w;
    }
  }
  float bq = qb[oc], bv = vb[oc];
  int hh = oc >> 5, d = oc & 31;
  for (int t = 0; t < 8; t++) {
    int n = n0 + t;
    size_t idx = ((size_t)(wl * NHD_ + hh) * NT_ + n) * HD_ + d;  // chunk-local
    qo[idx] = accq[t] + bq;
    ko[idx] = acck[t];
    vo[idx] = accv[t] + bv;
  }
}

// ---------------- kernel 4: windowed cosine attention (chunk-local in and out) ----------------
__global__ __launch_bounds__(64) void attn_kernel(
    const float* __restrict__ qq, const float* __restrict__ kk_, const float* __restrict__ vv_,
    const float* __restrict__ ls, const float* __restrict__ rpb, float* __restrict__ attn_out, int w0) {
  __shared__ float ks[NT_][HD_];
  __shared__ float vs[NT_][HD_];
  int bid = blockIdx.x;          // nw*8 = wl*NH+h
  int wl = bid >> 3, h = bid & 7;
  int w = w0 + wl;               // global window
  int i = threadIdx.x;           // 64
  size_t base = (size_t)bid * (NT_ * HD_) + (size_t)i * HD_;  // chunk-local

  float qr[HD_];
  float ss = 0.f;
#pragma unroll
  for (int d = 0; d < HD_; d += 4) {
    float4 f = *reinterpret_cast<const float4*>(qq + base + d);
    qr[d] = f.x; qr[d + 1] = f.y; qr[d + 2] = f.z; qr[d + 3] = f.w;
    ss += f.x * f.x + f.y * f.y + f.z * f.z + f.w * f.w;
  }
  float inv = 1.0f / fmaxf(sqrtf(ss), 1e-12f);
#pragma unroll
  for (int d = 0; d < HD_; d++) qr[d] *= inv;

  float kr[HD_]; ss = 0.f;
#pragma unroll
  for (int d = 0; d < HD_; d += 4) {
    float4 f = *reinterpret_cast<const float4*>(kk_ + base + d);
    kr[d] = f.x; kr[d + 1] = f.y; kr[d + 2] = f.z; kr[d + 3] = f.w;
    ss += f.x * f.x + f.y * f.y + f.z * f.z + f.w * f.w;
  }
  inv = 1.0f / fmaxf(sqrtf(ss), 1e-12f);
#pragma unroll
  for (int d = 0; d < HD_; d += 4) {
    float4 t; t.x = kr[d] * inv; t.y = kr[d + 1] * inv; t.z = kr[d + 2] * inv; t.w = kr[d + 3] * inv;
    *reinterpret_cast<float4*>(&ks[i][d]) = t;
  }
#pragma unroll
  for (int d = 0; d < HD_; d += 4) {
    float4 f = *reinterpret_cast<const float4*>(vv_ + base + d);
    *reinterpret_cast<float4*>(&vs[i][d]) = f;
  }
  __syncthreads();

  float scale = expf(fminf(ls[h], 4.605170185988091f));  // clamp at log(100)
  const float* rp = rpb + (((h << 6) + i) << 6);
  int win = w & 63, wh = win >> 3, ww = win & 7;
  int regi = region9(wh * 8 + (i >> 3), ww * 8 + (i & 7));

  // pass 1: online max + denom
  float m = -1e30f, l = 0.f;
  for (int j = 0; j < NT_; j++) {
    float dot = dot32(qr, &ks[j][0]);
    int regj = region9(wh * 8 + (j >> 3), ww * 8 + (j & 7));
    float val = dot * scale + rp[j] + (regj == regi ? 0.f : -100.f);
    float nm = fmaxf(m, val);
    l = l * expf(m - nm) + expf(val - nm);
    m = nm;
  }
  float rl = 1.0f / l;

  // pass 2: recompute probs, accumulate P·V
  float acc[HD_];
#pragma unroll
  for (int d = 0; d < HD_; d++) acc[d] = 0.f;
  for (int j = 0; j < NT_; j++) {
    float dot = dot32(qr, &ks[j][0]);
    int regj = region9(wh * 8 + (j >> 3), ww * 8 + (j & 7));
    float val = dot * scale + rp[j] + (regj == regi ? 0.f : -100.f);
    float p = expf(val - m) * rl;
#pragma unroll
    for (int d = 0; d < HD_; d += 4) {
      float4 vvv = *reinterpret_cast<const float4*>(&vs[j][d]);
      acc[d] += p * vvv.x; acc[d + 1] += p * vvv.y; acc[d + 2] += p * vvv.z; acc[d + 3] += p * vvv.w;
    }
  }
  // chunk-local token index; layout [n, C] per window
  float* op = attn_out + ((size_t)(wl * NT_ + i)) * CC_ + h * HD_;
#pragma unroll
  for (int d = 0; d < HD_; d += 4) {
    float4 t; t.x = acc[d]; t.y = acc[d + 1]; t.z = acc[d + 2]; t.w = acc[d + 3];
    *reinterpret_cast<float4*>(op + d) = t;
  }
}

// ---------------- kernel 5: proj + window-reverse + LN(norm1) + residual -> x1 (= d_out, fp32) ----------------
__global__ __launch_bounds__(256) void proj_kernel(
    const float* __restrict__ attn_out, const float* __restrict__ pw, const float* __restrict__ pb,
    const float* __restrict__ g, const float* __restrict__ bb,
    const float* __restrict__ x, float* __restrict__ x1, int w0) {
  __shared__ float as_[8][CC_];
  __shared__ float ps[8][CC_];
  int blk = blockIdx.x;          // nw*8
  int wl = blk >> 3;
  int w = w0 + wl;
  int n0 = (blk & 7) << 3;
  int tid = threadIdx.x;
  for (int t = 0; t < 8; t++)
    as_[t][tid] = attn_out[((size_t)(wl * NT_ + n0 + t)) * CC_ + tid];  // chunk-local
  __syncthreads();
  float acc[8];
#pragma unroll
  for (int t = 0; t < 8; t++) acc[t] = 0.f;
  const float* wr = pw + (size_t)tid * CC_;
  for (int c0 = 0; c0 < CC_; c0 += 4) {
    float4 f = *reinterpret_cast<const float4*>(wr + c0);
#pragma unroll
    for (int t = 0; t < 8; t++) {
      float4 xt = *reinterpret_cast<const float4*>(&as_[t][c0]);
      acc[t] += xt.x * f.x + xt.y * f.y + xt.z * f.z + xt.w * f.w;
    }
  }
  float pbv = pb[tid];
#pragma unroll
  for (int t = 0; t < 8; t++) ps[t][tid] = acc[t] + pbv;
  __syncthreads();

  int wv = tid >> 6, lane = tid & 63;
  int b = w >> 6, win = w & 63, wh = win >> 3, ww = win & 7;
  for (int tt = 0; tt < 2; tt++) {
    int t = wv * 2 + tt;
    int n = n0 + t;
    float sum = 0.f, sq = 0.f;
#pragma unroll
    for (int kk = 0; kk < 4; kk++) { float v = ps[t][lane + 64 * kk]; sum += v; sq += v * v; }
#pragma unroll
    for (int off = 1; off < 64; off <<= 1) {
      sum += __shfl_xor(sum, off, 64);
      sq  += __shfl_xor(sq, off, 64);
    }
    float mean = sum * (1.0f / CC_);
    float var = sq * (1.0f / CC_) - mean * mean;
    float rs = rsqrtf(fmaxf(var, 0.0f) + 1e-5f);
    int sh = wh * 8 + (n >> 3), sw = ww * 8 + (n & 7);
    int hh = (sh + SHIFT_) & 63, wc = (sw + SHIFT_) & 63;
    size_t tok = ((size_t)b << 12) + (hh << 6) + wc;
#pragma unroll
    for (int kk = 0; kk < 4; kk++) {
      int c = lane + 64 * kk;
      float y = (ps[t][c] - mean) * rs * g[c] + bb[c];
      x1[tok * CC_ + c] = x[tok * CC_ + c] + y;
    }
  }
}

// ---------------- kernel 6: MLP via bf16 MFMA (fc1+gelu+fc2) + LN(norm2) + residual; in-place on d_out ----------------
// Block: 64 tokens, 512 threads = 8 waves (2 row-waves x 4 col-waves).
// Chunked over hidden: 8 chunks of 128. fc2 accumulates fp32 across chunks in MFMA regs.
#define BM_   64
#define PADX_ 264   // 256 + 8 bf16 pad -> row stride 528B (4-bank skew, 2-way aliasing only)
#define PADH_ 136   // 128 + 8 bf16 pad -> row stride 272B

__global__ __launch_bounds__(512) void mlp_mfma_kernel(
    const float* __restrict__ x1,
    const u16* __restrict__ w1bf, const float* __restrict__ b1,
    const u16* __restrict__ w2bf, const float* __restrict__ b2,
    const float* __restrict__ g, const float* __restrict__ bb,
    float* __restrict__ out) {
  __shared__ union {
    struct { u16 xs[BM_][PADX_]; u16 hid[BM_][PADH_]; } s;   // 51200 B, live during chunk loop
    float po[BM_][CC_];                                      // 65536 B, live in epilogue only
  } sm;

  int tid = threadIdx.x;
  int lane = tid & 63;
  int wid = tid >> 6;        // 0..7
  int wm = wid >> 2;         // 0..1 : token rows [wm*32, wm*32+32)
  int wn = wid & 3;          // 0..3 : col quarter
  int lr = lane & 15;        // fragment row/col
  int lk = lane >> 4;        // k-group (k offset lk*8)
  size_t t0 = (size_t)blockIdx.x * BM_;

  // ---- stage x1 tile -> bf16 LDS ----
#pragma unroll
  for (int i = 0; i < 8; i++) {
    int idx = tid + i * 512;          // float4 index, 0..4095
    int row = idx >> 6;
    int c4 = idx & 63;
    float4 f = *reinterpret_cast<const float4*>(x1 + (t0 + row) * CC_ + c4 * 4);
    u32 p0 = (u32)f2bf(f.x) | ((u32)f2bf(f.y) << 16);
    u32 p1 = (u32)f2bf(f.z) | ((u32)f2bf(f.w) << 16);
    *reinterpret_cast<uint2*>(&sm.s.xs[row][c4 * 4]) = make_uint2(p0, p1);
  }
  __syncthreads();

  f32x4 acc2[2][4];
#pragma unroll
  for (int mf = 0; mf < 2; mf++)
#pragma unroll
    for (int nf = 0; nf < 4; nf++) acc2[mf][nf] = (f32x4){0.f, 0.f, 0.f, 0.f};

  for (int ch = 0; ch < 8; ch++) {
    int h0 = ch * 128;
    // ---- fc1: [64,256] x [128 chunk of 1024, 256]^T -> per-wave 32x32 ----
    f32x4 acc1[2][2];
#pragma unroll
    for (int mf = 0; mf < 2; mf++)
#pragma unroll
      for (int nf = 0; nf < 2; nf++) acc1[mf][nf] = (f32x4){0.f, 0.f, 0.f, 0.f};
#pragma unroll
    for (int k0 = 0; k0 < CC_; k0 += 32) {
      bf16x8 a0 = *reinterpret_cast<const bf16x8*>(&sm.s.xs[wm * 32 + lr][k0 + lk * 8]);
      bf16x8 a1 = *reinterpret_cast<const bf16x8*>(&sm.s.xs[wm * 32 + 16 + lr][k0 + lk * 8]);
      bf16x8 b0 = *reinterpret_cast<const bf16x8*>(w1bf + (size_t)(h0 + wn * 32 + lr) * CC_ + k0 + lk * 8);
      bf16x8 b1f = *reinterpret_cast<const bf16x8*>(w1bf + (size_t)(h0 + wn * 32 + 16 + lr) * CC_ + k0 + lk * 8);
      acc1[0][0] = __builtin_amdgcn_mfma_f32_16x16x32_bf16(a0, b0, acc1[0][0], 0, 0, 0);
      acc1[1][0] = __builtin_amdgcn_mfma_f32_16x16x32_bf16(a1, b0, acc1[1][0], 0, 0, 0);
      acc1[0][1] = __builtin_amdgcn_mfma_f32_16x16x32_bf16(a0, b1f, acc1[0][1], 0, 0, 0);
      acc1[1][1] = __builtin_amdgcn_mfma_f32_16x16x32_bf16(a1, b1f, acc1[1][1], 0, 0, 0);
    }
    // wait: previous chunk's fc2 reads of hid must be done before overwrite
    __syncthreads();
    float bias0 = b1[h0 + wn * 32 + lr];
    float bias1 = b1[h0 + wn * 32 + 16 + lr];
#pragma unroll
    for (int mf = 0; mf < 2; mf++)
#pragma unroll
      for (int nf = 0; nf < 2; nf++) {
        float bv = nf ? bias1 : bias0;
        int col = wn * 32 + nf * 16 + lr;
#pragma unroll
        for (int r = 0; r < 4; r++) {
          int row = wm * 32 + mf * 16 + lk * 4 + r;
          float v = acc1[mf][nf][r] + bv;
          v = 0.5f * v * (1.0f + erff(v * 0.7071067811865475f));   // exact gelu
          sm.s.hid[row][col] = f2bf(v);
        }
      }
    __syncthreads();
    // ---- fc2 partial: [64,128] x [256, 128 chunk]^T, accumulate ----
#pragma unroll
    for (int k0 = 0; k0 < 128; k0 += 32) {
      bf16x8 a0 = *reinterpret_cast<const bf16x8*>(&sm.s.hid[wm * 32 + lr][k0 + lk * 8]);
      bf16x8 a1 = *reinterpret_cast<const bf16x8*>(&sm.s.hid[wm * 32 + 16 + lr][k0 + lk * 8]);
#pragma unroll
      for (int nf = 0; nf < 4; nf++) {
        bf16x8 bf = *reinterpret_cast<const bf16x8*>(w2bf + (size_t)(wn * 64 + nf * 16 + lr) * HID_ + h0 + k0 + lk * 8);
        acc2[0][nf] = __builtin_amdgcn_mfma_f32_16x16x32_bf16(a0, bf, acc2[0][nf], 0, 0, 0);
        acc2[1][nf] = __builtin_amdgcn_mfma_f32_16x16x32_bf16(a1, bf, acc2[1][nf], 0, 0, 0);
      }
    }
  }
  __syncthreads();   // hid/xs dead; union becomes po

  // ---- write fc2 result + bias to po ----
#pragma unroll
  for (int mf = 0; mf < 2; mf++)
#pragma unroll
    for (int nf = 0; nf < 4; nf++) {
      int col = wn * 64 + nf * 16 + lr;
      float bv = b2[col];
#pragma unroll
      for (int r = 0; r < 4; r++) {
        int row = wm * 32 + mf * 16 + lk * 4 + r;
        sm.po[row][col] = acc2[mf][nf][r] + bv;
      }
    }
  __syncthreads();

  // ---- LN(norm2) + residual; 8 lanes per token, token-rotated float4 slots (conflict-free) ----
  int t = wid * 8 + (lane >> 3);
  int j8 = ((lane & 7) + (lane >> 3)) & 7;   // rotate slot by token -> banks disjoint across tokens
  float4 pv[8];
  float sum = 0.f, sq = 0.f;
#pragma unroll
  for (int i = 0; i < 8; i++) {
    float4 v = *reinterpret_cast<const float4*>(&sm.po[t][j8 * 4 + i * 32]);
    pv[i] = v;
    sum += v.x + v.y + v.z + v.w;
    sq += v.x * v.x + v.y * v.y + v.z * v.z + v.w * v.w;
  }
#pragma unroll
  for (int off = 1; off < 8; off <<= 1) {
    sum += __shfl_xor(sum, off, 8);
    sq  += __shfl_xor(sq, off, 8);
  }
  float mean = sum * (1.0f / CC_);
  float var = sq * (1.0f / CC_) - mean * mean;
  float rs = rsqrtf(fmaxf(var, 0.0f) + 1e-5f);
  const float* xrow = x1 + (t0 + t) * CC_;
  float* orow = out + (t0 + t) * CC_;
#pragma unroll
  for (int i = 0; i < 8; i++) {
    int c = j8 * 4 + i * 32;
    float4 xg = *reinterpret_cast<const float4*>(xrow + c);
    float4 gg = *reinterpret_cast<const float4*>(g + c);
    float4 bv = *reinterpret_cast<const float4*>(bb + c);
    float4 r;
    r.x = xg.x + (pv[i].x - mean) * rs * gg.x + bv.x;
    r.y = xg.y + (pv[i].y - mean) * rs * gg.y + bv.y;
    r.z = xg.z + (pv[i].z - mean) * rs * gg.z + bv.z;
    r.w = xg.w + (pv[i].w - mean) * rs * gg.w + bv.w;
    *reinterpret_cast<float4*>(orow + c) = r;
  }
}

extern "C" void kernel_launch(void* const* d_in, const int* in_sizes, int n_in,
                              void* d_out, int out_size, void* d_ws, size_t ws_size,
                              hipStream_t stream) {
  const float* x       = (const float*)d_in[0];
  const float* qkv_w   = (const float*)d_in[1];
  const float* q_bias  = (const float*)d_in[2];
  const float* v_bias  = (const float*)d_in[3];
  const float* logit_s = (const float*)d_in[4];
  const float* cpb_w1  = (const float*)d_in[5];
  const float* cpb_b1  = (const float*)d_in[6];
  const float* cpb_w2  = (const float*)d_in[7];
  const float* proj_w  = (const float*)d_in[8];
  const float* proj_b  = (const float*)d_in[9];
  const float* n1g     = (const float*)d_in[10];
  const float* n1b     = (const float*)d_in[11];
  const float* n2g     = (const float*)d_in[12];
  const float* n2b     = (const float*)d_in[13];
  const float* fc1_w   = (const float*)d_in[14];
  const float* fc1_b   = (const float*)d_in[15];
  const float* fc2_w   = (const float*)d_in[16];
  const float* fc2_b   = (const float*)d_in[17];
  float* out = (float*)d_out;
  char* ws = (char*)d_ws;

  // Workspace layout:
  //   [0,      8192): bias_table (fp32, 7200B used)
  //   [8192, 139264): rpb        (fp32, 8*64*64)
  //   [139264, 663552):  fc1_w bf16 (1024*256*2)
  //   [663552, 1187840): fc2_w bf16 (256*1024*2)
  //   [1187840, ...):  per-chunk q,k,v,attn_out (fp32), nc windows each
  u16* fc1bf = (u16*)(ws + 139264);
  u16* fc2bf = (u16*)(ws + 139264 + 524288);
  const size_t OFF_CH = 139264 + 1048576;
  const size_t ELEM_PER_WIN = (size_t)NHD_ * NT_ * HD_;      // 16384 fp32 elems per buffer per window
  const size_t PER_WIN_BYTES = 4 * ELEM_PER_WIN * 4;         // q+k+v+attn = 262144 B/window

  float* bias_table = (float*)(ws);
  float* rpb        = (float*)(ws + 8192);

  long long avail = (long long)ws_size - (long long)OFF_CH;
  long long ncw = avail / (long long)PER_WIN_BYTES;
  if (ncw < 1) ncw = 1;
  if (ncw > BW_) ncw = BW_;
  int nc = (int)ncw;   // windows per chunk — depends only on ws_size (graph-safe)

  float* qc = (float*)(ws + OFF_CH);
  float* kc = qc + (size_t)nc * ELEM_PER_WIN;
  float* vc = kc + (size_t)nc * ELEM_PER_WIN;
  float* ac = vc + (size_t)nc * ELEM_PER_WIN;

  cpb_kernel<<<225, 512, 0, stream>>>(cpb_w1, cpb_b1, cpb_w2, bias_table);
  rpb_kernel<<<NHD_ * NT_, 64, 0, stream>>>(bias_table, rpb);
  convw_kernel<<<1024, 256, 0, stream>>>(fc1_w, fc1bf, HID_ * CC_);
  convw_kernel<<<1024, 256, 0, stream>>>(fc2_w, fc2bf, CC_ * HID_);

  for (int w0 = 0; w0 < BW_; w0 += nc) {
    int nw = (BW_ - w0 < nc) ? (BW_ - w0) : nc;
    qkv_kernel<<<nw * 8, 256, 0, stream>>>(x, qkv_w, q_bias, v_bias, qc, kc, vc, w0);
    attn_kernel<<<nw * 8, 64, 0, stream>>>(qc, kc, vc, logit_s, rpb, ac, w0);
    proj_kernel<<<nw * 8, 256, 0, stream>>>(ac, proj_w, proj_b, n1g, n1b, x, out, w0);
  }
  mlp_mfma_kernel<<<TOK_ / BM_, 512, 0, stream>>>(out, fc1bf, fc1_b, fc2bf, fc2_b, n2g, n2b, out);
}

// Round 2
// 1793.826 us; speedup vs baseline: 4.8278x; 2.7373x over previous
//
#include <hip/hip_runtime.h>

typedef unsigned short u16;
typedef unsigned int u32;
typedef __attribute__((ext_vector_type(8))) short bf16x8;
typedef __attribute__((ext_vector_type(4))) float f32x4;

#define CC_    256         // channels
#define NHD_   8           // heads
#define NT_    64          // tokens per window
#define HD_    32          // head dim
#define HID_   1024        // mlp hidden
#define CPBH_  512         // cpb hidden
#define BW_    2048        // total windows = 32 * 64
#define TOK_   131072      // total tokens
#define SHIFT_ 4

// region id (0..8) in the shifted canvas for mask construction
__device__ __forceinline__ int region9(int ph, int pw) {
  return (ph < 56 ? 0 : (ph < 60 ? 3 : 6)) + (pw < 56 ? 0 : (pw < 60 ? 1 : 2));
}
__device__ __forceinline__ float dot32(const float* qr, const float* krow) {
  float d0 = 0.f, d1 = 0.f, d2 = 0.f, d3 = 0.f;
#pragma unroll
  for (int d = 0; d < HD_; d += 4) {
    float4 kk = *reinterpret_cast<const float4*>(krow + d);
    d0 += qr[d] * kk.x; d1 += qr[d + 1] * kk.y;
    d2 += qr[d + 2] * kk.z; d3 += qr[d + 3] * kk.w;
  }
  return (d0 + d1) + (d2 + d3);
}

// fp32 -> bf16 round-to-nearest-even (finite values only)
__device__ __forceinline__ u16 f2bf(float f) {
  u32 u = __builtin_bit_cast(u32, f);
  u = (u + 0x7FFFu + ((u >> 16) & 1u)) >> 16;
  return (u16)u;
}

// split a float4 into bf16 hi + bf16 lo (x ~= hi + lo, rel err ~2^-16)
__device__ __forceinline__ void split4(float4 f, uint2& hi, uint2& lo) {
  u16 h0 = f2bf(f.x), h1 = f2bf(f.y), h2 = f2bf(f.z), h3 = f2bf(f.w);
  float r0 = f.x - __builtin_bit_cast(float, (u32)h0 << 16);
  float r1 = f.y - __builtin_bit_cast(float, (u32)h1 << 16);
  float r2 = f.z - __builtin_bit_cast(float, (u32)h2 << 16);
  float r3 = f.w - __builtin_bit_cast(float, (u32)h3 << 16);
  hi = make_uint2((u32)h0 | ((u32)h1 << 16), (u32)h2 | ((u32)h3 << 16));
  lo = make_uint2((u32)f2bf(r0) | ((u32)f2bf(r1) << 16),
                  (u32)f2bf(r2) | ((u32)f2bf(r3) << 16));
}

// ---------------- kernel 1: CPB MLP -> bias_table[225][8] ----------------
__global__ void cpb_kernel(const float* __restrict__ w1, const float* __restrict__ b1,
                           const float* __restrict__ w2, float* __restrict__ bias_table) {
  __shared__ float hid[CPBH_];
  int p = blockIdx.x;        // 0..224
  int k = threadIdx.x;       // 0..511
  int hi = p / 15, wi = p % 15;
  float a0 = (float)(hi - 7) / 7.0f * 8.0f;
  float a1 = (float)(wi - 7) / 7.0f * 8.0f;
  float t0 = (a0 == 0.0f) ? 0.0f : copysignf(log2f(fabsf(a0) + 1.0f) / 3.0f, a0);
  float t1 = (a1 == 0.0f) ? 0.0f : copysignf(log2f(fabsf(a1) + 1.0f) / 3.0f, a1);
  float h = t0 * w1[2 * k] + t1 * w1[2 * k + 1] + b1[k];
  hid[k] = fmaxf(h, 0.0f);
  __syncthreads();
  if (k < NHD_) {
    float s = 0.0f;
    for (int j = 0; j < CPBH_; j++) s += hid[j] * w2[k * CPBH_ + j];
    bias_table[p * NHD_ + k] = s;
  }
}

// ---------------- kernel 2: gather + sigmoid -> rpb[8][64][64] ----------------
__global__ void rpb_kernel(const float* __restrict__ bias_table, float* __restrict__ rpb) {
  int h = blockIdx.x >> 6;   // grid 512
  int i = blockIdx.x & 63;
  int j = threadIdx.x;       // 64
  int dih = (i >> 3) - (j >> 3) + 7;
  int diw = (i & 7) - (j & 7) + 7;
  float v = bias_table[(dih * 15 + diw) * NHD_ + h];
  rpb[(((h << 6) + i) << 6) + j] = 16.0f / (1.0f + expf(-v));
}

// ---------------- weight fp32 -> bf16 conversion (single) ----------------
__global__ void convw_kernel(const float* __restrict__ w, u16* __restrict__ o, int n) {
  int i = blockIdx.x * 256 + threadIdx.x;
  if (i < n) o[i] = f2bf(w[i]);
}

// ---------------- weight fp32 -> bf16 hi/lo split ----------------
__global__ void convsplit_kernel(const float* __restrict__ w, u16* __restrict__ hi,
                                 u16* __restrict__ lo, int n) {
  int i = blockIdx.x * 256 + threadIdx.x;
  if (i < n) {
    float v = w[i];
    u16 h = f2bf(v);
    hi[i] = h;
    lo[i] = f2bf(v - __builtin_bit_cast(float, (u32)h << 16));
  }
}

// ---------------- kernel 3: shifted-window gather + QKV GEMM via split-bf16 MFMA ----------------
// One window (64 tokens) per block, 512 threads = 8 waves; wave w owns output cols [w*96, w*96+96).
// X staged in LDS as bf16 hi/lo with 16B-unit XOR swizzle (u ^= row&7) -> 64KB total, <=2-way banks.
__global__ __launch_bounds__(512) void qkv_mfma_kernel(
    const float* __restrict__ x,
    const u16* __restrict__ wh_, const u16* __restrict__ wl_,
    const float* __restrict__ qb, const float* __restrict__ vb,
    float* __restrict__ qo, float* __restrict__ ko, float* __restrict__ vo, int w0) {
  __shared__ u16 xh[64 * 256];
  __shared__ u16 xl[64 * 256];
  int tid = threadIdx.x;
  int lane = tid & 63, wid = tid >> 6;
  int lr = lane & 15, lk = lane >> 4;
  int wl2 = blockIdx.x;          // chunk-local window
  int w = w0 + wl2;
  int b = w >> 6, win = w & 63, wwh = win >> 3, www = win & 7;

#pragma unroll
  for (int i = 0; i < 8; i++) {
    int idx = tid + i * 512;     // float4 unit 0..4095
    int n = idx >> 6, c4 = idx & 63;
    int sh = wwh * 8 + (n >> 3), sw = www * 8 + (n & 7);
    int hh = (sh + SHIFT_) & 63, wc = (sw + SHIFT_) & 63;
    float4 f = *reinterpret_cast<const float4*>(
        x + ((size_t)((b << 12) + (hh << 6) + wc)) * CC_ + c4 * 4);
    uint2 hi, lo; split4(f, hi, lo);
    int u = c4 >> 1;             // 16B unit 0..31
    int off16 = n * 256 + ((u ^ (n & 7)) << 3) + ((c4 & 1) << 2);
    *reinterpret_cast<uint2*>(&xh[off16]) = hi;
    *reinterpret_cast<uint2*>(&xl[off16]) = lo;
  }
  __syncthreads();

  f32x4 acc[4][6];
#pragma unroll
  for (int m = 0; m < 4; m++)
#pragma unroll
    for (int nf = 0; nf < 6; nf++) acc[m][nf] = (f32x4){0.f, 0.f, 0.f, 0.f};

  for (int k0 = 0; k0 < CC_; k0 += 32) {
    int u0 = (k0 >> 3) + lk;
    bf16x8 ah[4], al[4];
#pragma unroll
    for (int m = 0; m < 4; m++) {
      int row = m * 16 + lr;
      int off16 = row * 256 + ((u0 ^ (row & 7)) << 3);
      ah[m] = *reinterpret_cast<const bf16x8*>(&xh[off16]);
      al[m] = *reinterpret_cast<const bf16x8*>(&xl[off16]);
    }
#pragma unroll
    for (int nf = 0; nf < 6; nf++) {
      int col = wid * 96 + nf * 16 + lr;
      size_t wo = (size_t)col * CC_ + k0 + lk * 8;
      bf16x8 bh = *reinterpret_cast<const bf16x8*>(wh_ + wo);
      bf16x8 bl = *reinterpret_cast<const bf16x8*>(wl_ + wo);
#pragma unroll
      for (int m = 0; m < 4; m++) {
        acc[m][nf] = __builtin_amdgcn_mfma_f32_16x16x32_bf16(ah[m], bh, acc[m][nf], 0, 0, 0);
        acc[m][nf] = __builtin_amdgcn_mfma_f32_16x16x32_bf16(al[m], bh, acc[m][nf], 0, 0, 0);
        acc[m][nf] = __builtin_amdgcn_mfma_f32_16x16x32_bf16(ah[m], bl, acc[m][nf], 0, 0, 0);
      }
    }
  }

#pragma unroll
  for (int nf = 0; nf < 6; nf++) {
    int col = wid * 96 + nf * 16 + lr;     // 16-col frag never straddles a 256 boundary
    int mat = col >> 8, cc = col & 255;
    float bias = (mat == 0) ? qb[cc] : ((mat == 2) ? vb[cc] : 0.f);
    float* dst = (mat == 0) ? qo : ((mat == 1) ? ko : vo);
    int hd = cc >> 5, d = cc & 31;
    float* dp = dst + ((size_t)(wl2 * NHD_ + hd) * NT_) * HD_ + d;
#pragma unroll
    for (int m = 0; m < 4; m++)
#pragma unroll
      for (int r = 0; r < 4; r++) {
        int n = m * 16 + lk * 4 + r;
        dp[(size_t)n * HD_] = acc[m][nf][r] + bias;
      }
  }
}

// ---------------- kernel 4: windowed cosine attention (chunk-local in and out) ----------------
__global__ __launch_bounds__(64) void attn_kernel(
    const float* __restrict__ qq, const float* __restrict__ kk_, const float* __restrict__ vv_,
    const float* __restrict__ ls, const float* __restrict__ rpb, float* __restrict__ attn_out, int w0) {
  __shared__ float ks[NT_][HD_];
  __shared__ float vs[NT_][HD_];
  int bid = blockIdx.x;          // nw*8 = wl*NH+h
  int wl = bid >> 3, h = bid & 7;
  int w = w0 + wl;               // global window
  int i = threadIdx.x;           // 64
  size_t base = (size_t)bid * (NT_ * HD_) + (size_t)i * HD_;  // chunk-local

  float qr[HD_];
  float ss = 0.f;
#pragma unroll
  for (int d = 0; d < HD_; d += 4) {
    float4 f = *reinterpret_cast<const float4*>(qq + base + d);
    qr[d] = f.x; qr[d + 1] = f.y; qr[d + 2] = f.z; qr[d + 3] = f.w;
    ss += f.x * f.x + f.y * f.y + f.z * f.z + f.w * f.w;
  }
  float inv = 1.0f / fmaxf(sqrtf(ss), 1e-12f);
#pragma unroll
  for (int d = 0; d < HD_; d++) qr[d] *= inv;

  float kr[HD_]; ss = 0.f;
#pragma unroll
  for (int d = 0; d < HD_; d += 4) {
    float4 f = *reinterpret_cast<const float4*>(kk_ + base + d);
    kr[d] = f.x; kr[d + 1] = f.y; kr[d + 2] = f.z; kr[d + 3] = f.w;
    ss += f.x * f.x + f.y * f.y + f.z * f.z + f.w * f.w;
  }
  inv = 1.0f / fmaxf(sqrtf(ss), 1e-12f);
#pragma unroll
  for (int d = 0; d < HD_; d += 4) {
    float4 t; t.x = kr[d] * inv; t.y = kr[d + 1] * inv; t.z = kr[d + 2] * inv; t.w = kr[d + 3] * inv;
    *reinterpret_cast<float4*>(&ks[i][d]) = t;
  }
#pragma unroll
  for (int d = 0; d < HD_; d += 4) {
    float4 f = *reinterpret_cast<const float4*>(vv_ + base + d);
    *reinterpret_cast<float4*>(&vs[i][d]) = f;
  }
  __syncthreads();

  float scale = expf(fminf(ls[h], 4.605170185988091f));  // clamp at log(100)
  const float* rp = rpb + (((h << 6) + i) << 6);
  int win = w & 63, wh = win >> 3, ww = win & 7;
  int regi = region9(wh * 8 + (i >> 3), ww * 8 + (i & 7));

  // pass 1: online max + denom
  float m = -1e30f, l = 0.f;
  for (int j = 0; j < NT_; j++) {
    float dot = dot32(qr, &ks[j][0]);
    int regj = region9(wh * 8 + (j >> 3), ww * 8 + (j & 7));
    float val = dot * scale + rp[j] + (regj == regi ? 0.f : -100.f);
    float nm = fmaxf(m, val);
    l = l * expf(m - nm) + expf(val - nm);
    m = nm;
  }
  float rl = 1.0f / l;

  // pass 2: recompute probs, accumulate P·V
  float acc[HD_];
#pragma unroll
  for (int d = 0; d < HD_; d++) acc[d] = 0.f;
  for (int j = 0; j < NT_; j++) {
    float dot = dot32(qr, &ks[j][0]);
    int regj = region9(wh * 8 + (j >> 3), ww * 8 + (j & 7));
    float val = dot * scale + rp[j] + (regj == regi ? 0.f : -100.f);
    float p = expf(val - m) * rl;
#pragma unroll
    for (int d = 0; d < HD_; d += 4) {
      float4 vvv = *reinterpret_cast<const float4*>(&vs[j][d]);
      acc[d] += p * vvv.x; acc[d + 1] += p * vvv.y; acc[d + 2] += p * vvv.z; acc[d + 3] += p * vvv.w;
    }
  }
  // chunk-local token index; layout [n, C] per window
  float* op = attn_out + ((size_t)(wl * NT_ + i)) * CC_ + h * HD_;
#pragma unroll
  for (int d = 0; d < HD_; d += 4) {
    float4 t; t.x = acc[d]; t.y = acc[d + 1]; t.z = acc[d + 2]; t.w = acc[d + 3];
    *reinterpret_cast<float4*>(op + d) = t;
  }
}

// ---------------- kernel 5: proj via split-bf16 MFMA + window-reverse + LN(norm1) + residual ----------------
// One window per block, 512 threads = 8 waves; wave w owns output cols [w*32, w*32+32).
__global__ __launch_bounds__(512) void proj_mfma_kernel(
    const float* __restrict__ attn_out,
    const u16* __restrict__ pwh, const u16* __restrict__ pwl, const float* __restrict__ pb,
    const float* __restrict__ g, const float* __restrict__ bb,
    const float* __restrict__ x, float* __restrict__ x1, int w0) {
  __shared__ union {
    struct { u16 ah[64 * 256]; u16 al[64 * 256]; } s;   // 64KB, live during GEMM
    float po[64][CC_];                                  // 64KB, live in epilogue
  } sm;
  int tid = threadIdx.x;
  int lane = tid & 63, wid = tid >> 6;
  int lr = lane & 15, lk = lane >> 4;
  int wl2 = blockIdx.x;
  int w = w0 + wl2;

#pragma unroll
  for (int i = 0; i < 8; i++) {
    int idx = tid + i * 512;
    int n = idx >> 6, c4 = idx & 63;
    float4 f = *reinterpret_cast<const float4*>(
        attn_out + ((size_t)(wl2 * NT_ + n)) * CC_ + c4 * 4);
    uint2 hi, lo; split4(f, hi, lo);
    int u = c4 >> 1;
    int off16 = n * 256 + ((u ^ (n & 7)) << 3) + ((c4 & 1) << 2);
    *reinterpret_cast<uint2*>(&sm.s.ah[off16]) = hi;
    *reinterpret_cast<uint2*>(&sm.s.al[off16]) = lo;
  }
  __syncthreads();

  f32x4 acc[4][2];
#pragma unroll
  for (int m = 0; m < 4; m++)
#pragma unroll
    for (int nf = 0; nf < 2; nf++) acc[m][nf] = (f32x4){0.f, 0.f, 0.f, 0.f};

  for (int k0 = 0; k0 < CC_; k0 += 32) {
    int u0 = (k0 >> 3) + lk;
    bf16x8 ah[4], al[4];
#pragma unroll
    for (int m = 0; m < 4; m++) {
      int row = m * 16 + lr;
      int off16 = row * 256 + ((u0 ^ (row & 7)) << 3);
      ah[m] = *reinterpret_cast<const bf16x8*>(&sm.s.ah[off16]);
      al[m] = *reinterpret_cast<const bf16x8*>(&sm.s.al[off16]);
    }
#pragma unroll
    for (int nf = 0; nf < 2; nf++) {
      int col = wid * 32 + nf * 16 + lr;
      size_t wo = (size_t)col * CC_ + k0 + lk * 8;
      bf16x8 bh = *reinterpret_cast<const bf16x8*>(pwh + wo);
      bf16x8 bl = *reinterpret_cast<const bf16x8*>(pwl + wo);
#pragma unroll
      for (int m = 0; m < 4; m++) {
        acc[m][nf] = __builtin_amdgcn_mfma_f32_16x16x32_bf16(ah[m], bh, acc[m][nf], 0, 0, 0);
        acc[m][nf] = __builtin_amdgcn_mfma_f32_16x16x32_bf16(al[m], bh, acc[m][nf], 0, 0, 0);
        acc[m][nf] = __builtin_amdgcn_mfma_f32_16x16x32_bf16(ah[m], bl, acc[m][nf], 0, 0, 0);
      }
    }
  }
  __syncthreads();   // staging dead; union becomes po

#pragma unroll
  for (int nf = 0; nf < 2; nf++) {
    int col = wid * 32 + nf * 16 + lr;
    float bv = pb[col];
#pragma unroll
    for (int m = 0; m < 4; m++)
#pragma unroll
      for (int r = 0; r < 4; r++)
        sm.po[m * 16 + lk * 4 + r][col] = acc[m][nf][r] + bv;
  }
  __syncthreads();

  // LN + window-reverse + residual; 8 lanes per token, token-rotated float4 slots
  int t = wid * 8 + (lane >> 3);
  int j8 = ((lane & 7) + (lane >> 3)) & 7;
  float4 pv[8];
  float sum = 0.f, sq = 0.f;
#pragma unroll
  for (int i = 0; i < 8; i++) {
    float4 v = *reinterpret_cast<const float4*>(&sm.po[t][j8 * 4 + i * 32]);
    pv[i] = v;
    sum += v.x + v.y + v.z + v.w;
    sq += v.x * v.x + v.y * v.y + v.z * v.z + v.w * v.w;
  }
#pragma unroll
  for (int off = 1; off < 8; off <<= 1) {
    sum += __shfl_xor(sum, off, 8);
    sq  += __shfl_xor(sq, off, 8);
  }
  float mean = sum * (1.0f / CC_);
  float var = sq * (1.0f / CC_) - mean * mean;
  float rs = rsqrtf(fmaxf(var, 0.0f) + 1e-5f);
  int b = w >> 6, win = w & 63, wwh = win >> 3, www = win & 7;
  int sh = wwh * 8 + (t >> 3), sw = www * 8 + (t & 7);
  int hh = (sh + SHIFT_) & 63, wc = (sw + SHIFT_) & 63;
  size_t tok = ((size_t)(b << 12)) + (hh << 6) + wc;
  const float* xrow = x + tok * CC_;
  float* orow = x1 + tok * CC_;
#pragma unroll
  for (int i = 0; i < 8; i++) {
    int c = j8 * 4 + i * 32;
    float4 xg = *reinterpret_cast<const float4*>(xrow + c);
    float4 gg = *reinterpret_cast<const float4*>(g + c);
    float4 bv = *reinterpret_cast<const float4*>(bb + c);
    float4 r;
    r.x = xg.x + (pv[i].x - mean) * rs * gg.x + bv.x;
    r.y = xg.y + (pv[i].y - mean) * rs * gg.y + bv.y;
    r.z = xg.z + (pv[i].z - mean) * rs * gg.z + bv.z;
    r.w = xg.w + (pv[i].w - mean) * rs * gg.w + bv.w;
    *reinterpret_cast<float4*>(orow + c) = r;
  }
}

// ---------------- kernel 6: MLP via bf16 MFMA (fc1+gelu+fc2) + LN(norm2) + residual ----------------
#define BM_   64
#define PADX_ 264   // 256 + 8 bf16 pad -> row stride 528B
#define PADH_ 136   // 128 + 8 bf16 pad -> row stride 272B

__global__ __launch_bounds__(512) void mlp_mfma_kernel(
    const float* __restrict__ x1,
    const u16* __restrict__ w1bf, const float* __restrict__ b1,
    const u16* __restrict__ w2bf, const float* __restrict__ b2,
    const float* __restrict__ g, const float* __restrict__ bb,
    float* __restrict__ out) {
  __shared__ union {
    struct { u16 xs[BM_][PADX_]; u16 hid[BM_][PADH_]; } s;   // 51200 B
    float po[BM_][CC_];                                      // 65536 B
  } sm;

  int tid = threadIdx.x;
  int lane = tid & 63;
  int wid = tid >> 6;
  int wm = wid >> 2;
  int wn = wid & 3;
  int lr = lane & 15;
  int lk = lane >> 4;
  size_t t0 = (size_t)blockIdx.x * BM_;

#pragma unroll
  for (int i = 0; i < 8; i++) {
    int idx = tid + i * 512;
    int row = idx >> 6;
    int c4 = idx & 63;
    float4 f = *reinterpret_cast<const float4*>(x1 + (t0 + row) * CC_ + c4 * 4);
    u32 p0 = (u32)f2bf(f.x) | ((u32)f2bf(f.y) << 16);
    u32 p1 = (u32)f2bf(f.z) | ((u32)f2bf(f.w) << 16);
    *reinterpret_cast<uint2*>(&sm.s.xs[row][c4 * 4]) = make_uint2(p0, p1);
  }
  __syncthreads();

  f32x4 acc2[2][4];
#pragma unroll
  for (int mf = 0; mf < 2; mf++)
#pragma unroll
    for (int nf = 0; nf < 4; nf++) acc2[mf][nf] = (f32x4){0.f, 0.f, 0.f, 0.f};

  for (int ch = 0; ch < 8; ch++) {
    int h0 = ch * 128;
    f32x4 acc1[2][2];
#pragma unroll
    for (int mf = 0; mf < 2; mf++)
#pragma unroll
      for (int nf = 0; nf < 2; nf++) acc1[mf][nf] = (f32x4){0.f, 0.f, 0.f, 0.f};
#pragma unroll
    for (int k0 = 0; k0 < CC_; k0 += 32) {
      bf16x8 a0 = *reinterpret_cast<const bf16x8*>(&sm.s.xs[wm * 32 + lr][k0 + lk * 8]);
      bf16x8 a1 = *reinterpret_cast<const bf16x8*>(&sm.s.xs[wm * 32 + 16 + lr][k0 + lk * 8]);
      bf16x8 b0 = *reinterpret_cast<const bf16x8*>(w1bf + (size_t)(h0 + wn * 32 + lr) * CC_ + k0 + lk * 8);
      bf16x8 b1f = *reinterpret_cast<const bf16x8*>(w1bf + (size_t)(h0 + wn * 32 + 16 + lr) * CC_ + k0 + lk * 8);
      acc1[0][0] = __builtin_amdgcn_mfma_f32_16x16x32_bf16(a0, b0, acc1[0][0], 0, 0, 0);
      acc1[1][0] = __builtin_amdgcn_mfma_f32_16x16x32_bf16(a1, b0, acc1[1][0], 0, 0, 0);
      acc1[0][1] = __builtin_amdgcn_mfma_f32_16x16x32_bf16(a0, b1f, acc1[0][1], 0, 0, 0);
      acc1[1][1] = __builtin_amdgcn_mfma_f32_16x16x32_bf16(a1, b1f, acc1[1][1], 0, 0, 0);
    }
    __syncthreads();
    float bias0 = b1[h0 + wn * 32 + lr];
    float bias1 = b1[h0 + wn * 32 + 16 + lr];
#pragma unroll
    for (int mf = 0; mf < 2; mf++)
#pragma unroll
      for (int nf = 0; nf < 2; nf++) {
        float bv = nf ? bias1 : bias0;
        int col = wn * 32 + nf * 16 + lr;
#pragma unroll
        for (int r = 0; r < 4; r++) {
          int row = wm * 32 + mf * 16 + lk * 4 + r;
          float v = acc1[mf][nf][r] + bv;
          v = 0.5f * v * (1.0f + erff(v * 0.7071067811865475f));
          sm.s.hid[row][col] = f2bf(v);
        }
      }
    __syncthreads();
#pragma unroll
    for (int k0 = 0; k0 < 128; k0 += 32) {
      bf16x8 a0 = *reinterpret_cast<const bf16x8*>(&sm.s.hid[wm * 32 + lr][k0 + lk * 8]);
      bf16x8 a1 = *reinterpret_cast<const bf16x8*>(&sm.s.hid[wm * 32 + 16 + lr][k0 + lk * 8]);
#pragma unroll
      for (int nf = 0; nf < 4; nf++) {
        bf16x8 bf = *reinterpret_cast<const bf16x8*>(w2bf + (size_t)(wn * 64 + nf * 16 + lr) * HID_ + h0 + k0 + lk * 8);
        acc2[0][nf] = __builtin_amdgcn_mfma_f32_16x16x32_bf16(a0, bf, acc2[0][nf], 0, 0, 0);
        acc2[1][nf] = __builtin_amdgcn_mfma_f32_16x16x32_bf16(a1, bf, acc2[1][nf], 0, 0, 0);
      }
    }
  }
  __syncthreads();

#pragma unroll
  for (int mf = 0; mf < 2; mf++)
#pragma unroll
    for (int nf = 0; nf < 4; nf++) {
      int col = wn * 64 + nf * 16 + lr;
      float bv = b2[col];
#pragma unroll
      for (int r = 0; r < 4; r++) {
        int row = wm * 32 + mf * 16 + lk * 4 + r;
        sm.po[row][col] = acc2[mf][nf][r] + bv;
      }
    }
  __syncthreads();

  int t = wid * 8 + (lane >> 3);
  int j8 = ((lane & 7) + (lane >> 3)) & 7;
  float4 pv[8];
  float sum = 0.f, sq = 0.f;
#pragma unroll
  for (int i = 0; i < 8; i++) {
    float4 v = *reinterpret_cast<const float4*>(&sm.po[t][j8 * 4 + i * 32]);
    pv[i] = v;
    sum += v.x + v.y + v.z + v.w;
    sq += v.x * v.x + v.y * v.y + v.z * v.z + v.w * v.w;
  }
#pragma unroll
  for (int off = 1; off < 8; off <<= 1) {
    sum += __shfl_xor(sum, off, 8);
    sq  += __shfl_xor(sq, off, 8);
  }
  float mean = sum * (1.0f / CC_);
  float var = sq * (1.0f / CC_) - mean * mean;
  float rs = rsqrtf(fmaxf(var, 0.0f) + 1e-5f);
  const float* xrow = x1 + (t0 + t) * CC_;
  float* orow = out + (t0 + t) * CC_;
#pragma unroll
  for (int i = 0; i < 8; i++) {
    int c = j8 * 4 + i * 32;
    float4 xg = *reinterpret_cast<const float4*>(xrow + c);
    float4 gg = *reinterpret_cast<const float4*>(g + c);
    float4 bv = *reinterpret_cast<const float4*>(bb + c);
    float4 r;
    r.x = xg.x + (pv[i].x - mean) * rs * gg.x + bv.x;
    r.y = xg.y + (pv[i].y - mean) * rs * gg.y + bv.y;
    r.z = xg.z + (pv[i].z - mean) * rs * gg.z + bv.z;
    r.w = xg.w + (pv[i].w - mean) * rs * gg.w + bv.w;
    *reinterpret_cast<float4*>(orow + c) = r;
  }
}

extern "C" void kernel_launch(void* const* d_in, const int* in_sizes, int n_in,
                              void* d_out, int out_size, void* d_ws, size_t ws_size,
                              hipStream_t stream) {
  const float* x       = (const float*)d_in[0];
  const float* qkv_w   = (const float*)d_in[1];
  const float* q_bias  = (const float*)d_in[2];
  const float* v_bias  = (const float*)d_in[3];
  const float* logit_s = (const float*)d_in[4];
  const float* cpb_w1  = (const float*)d_in[5];
  const float* cpb_b1  = (const float*)d_in[6];
  const float* cpb_w2  = (const float*)d_in[7];
  const float* proj_w  = (const float*)d_in[8];
  const float* proj_b  = (const float*)d_in[9];
  const float* n1g     = (const float*)d_in[10];
  const float* n1b     = (const float*)d_in[11];
  const float* n2g     = (const float*)d_in[12];
  const float* n2b     = (const float*)d_in[13];
  const float* fc1_w   = (const float*)d_in[14];
  const float* fc1_b   = (const float*)d_in[15];
  const float* fc2_w   = (const float*)d_in[16];
  const float* fc2_b   = (const float*)d_in[17];
  float* out = (float*)d_out;
  char* ws = (char*)d_ws;

  // Workspace layout:
  //   [0,      8192): bias_table
  //   [8192, 139264): rpb (8*64*64 fp32)
  //   [139264, 663552):  fc1_w bf16
  //   [663552, 1187840): fc2_w bf16
  //   [1187840, 1581056): qkv_w bf16 hi (768*256*2)
  //   [1581056, 1974272): qkv_w bf16 lo
  //   [1974272, 2105344): proj_w bf16 hi (256*256*2)
  //   [2105344, 2236416): proj_w bf16 lo
  //   [2236416, ...):  per-chunk q,k,v,attn_out (fp32), nc windows each
  u16* fc1bf = (u16*)(ws + 139264);
  u16* fc2bf = (u16*)(ws + 663552);
  u16* qwh   = (u16*)(ws + 1187840);
  u16* qwl   = (u16*)(ws + 1581056);
  u16* pwh   = (u16*)(ws + 1974272);
  u16* pwl   = (u16*)(ws + 2105344);
  const size_t OFF_CH = 2236416;
  const size_t ELEM_PER_WIN = (size_t)NHD_ * NT_ * HD_;      // 16384 fp32 elems per buffer per window
  const size_t PER_WIN_BYTES = 4 * ELEM_PER_WIN * 4;         // q+k+v+attn = 262144 B/window

  float* bias_table = (float*)(ws);
  float* rpb        = (float*)(ws + 8192);

  long long avail = (long long)ws_size - (long long)OFF_CH;
  long long ncw = avail / (long long)PER_WIN_BYTES;
  if (ncw < 1) ncw = 1;
  if (ncw > BW_) ncw = BW_;
  int nc = (int)ncw;   // windows per chunk — depends only on ws_size (graph-safe)

  float* qc = (float*)(ws + OFF_CH);
  float* kc = qc + (size_t)nc * ELEM_PER_WIN;
  float* vc = kc + (size_t)nc * ELEM_PER_WIN;
  float* ac = vc + (size_t)nc * ELEM_PER_WIN;

  cpb_kernel<<<225, 512, 0, stream>>>(cpb_w1, cpb_b1, cpb_w2, bias_table);
  rpb_kernel<<<NHD_ * NT_, 64, 0, stream>>>(bias_table, rpb);
  convw_kernel<<<1024, 256, 0, stream>>>(fc1_w, fc1bf, HID_ * CC_);
  convw_kernel<<<1024, 256, 0, stream>>>(fc2_w, fc2bf, CC_ * HID_);
  convsplit_kernel<<<768, 256, 0, stream>>>(qkv_w, qwh, qwl, 3 * CC_ * CC_);
  convsplit_kernel<<<256, 256, 0, stream>>>(proj_w, pwh, pwl, CC_ * CC_);

  for (int w0 = 0; w0 < BW_; w0 += nc) {
    int nw = (BW_ - w0 < nc) ? (BW_ - w0) : nc;
    qkv_mfma_kernel<<<nw, 512, 0, stream>>>(x, qwh, qwl, q_bias, v_bias, qc, kc, vc, w0);
    attn_kernel<<<nw * 8, 64, 0, stream>>>(qc, kc, vc, logit_s, rpb, ac, w0);
    proj_mfma_kernel<<<nw, 512, 0, stream>>>(ac, pwh, pwl, proj_b, n1g, n1b, x, out, w0);
  }
  mlp_mfma_kernel<<<TOK_ / BM_, 512, 0, stream>>>(out, fc1bf, fc1_b, fc2bf, fc2_b, n2g, n2b, out);
}

// Round 4
// 1673.436 us; speedup vs baseline: 5.1751x; 1.0719x over previous
//
#include <hip/hip_runtime.h>

typedef unsigned short u16;
typedef unsigned int u32;
typedef __attribute__((ext_vector_type(8))) short bf16x8;
typedef __attribute__((ext_vector_type(4))) float f32x4;

#define CC_    256         // channels
#define NHD_   8           // heads
#define NT_    64          // tokens per window
#define HD_    32          // head dim
#define HID_   1024        // mlp hidden
#define CPBH_  512         // cpb hidden
#define BW_    2048        // total windows = 32 * 64
#define TOK_   131072      // total tokens
#define SHIFT_ 4

// region id (0..8) in the shifted canvas for mask construction
__device__ __forceinline__ int region9(int ph, int pw) {
  return (ph < 56 ? 0 : (ph < 60 ? 3 : 6)) + (pw < 56 ? 0 : (pw < 60 ? 1 : 2));
}
__device__ __forceinline__ float dot32(const float* qr, const float* krow) {
  float d0 = 0.f, d1 = 0.f, d2 = 0.f, d3 = 0.f;
#pragma unroll
  for (int d = 0; d < HD_; d += 4) {
    float4 kk = *reinterpret_cast<const float4*>(krow + d);
    d0 += qr[d] * kk.x; d1 += qr[d + 1] * kk.y;
    d2 += qr[d + 2] * kk.z; d3 += qr[d + 3] * kk.w;
  }
  return (d0 + d1) + (d2 + d3);
}

// fp32 -> bf16 round-to-nearest-even (finite values only)
__device__ __forceinline__ u16 f2bf(float f) {
  u32 u = __builtin_bit_cast(u32, f);
  u = (u + 0x7FFFu + ((u >> 16) & 1u)) >> 16;
  return (u16)u;
}

// split a float4 into bf16 hi + bf16 lo (x ~= hi + lo, rel err ~2^-16)
__device__ __forceinline__ void split4(float4 f, uint2& hi, uint2& lo) {
  u16 h0 = f2bf(f.x), h1 = f2bf(f.y), h2 = f2bf(f.z), h3 = f2bf(f.w);
  float r0 = f.x - __builtin_bit_cast(float, (u32)h0 << 16);
  float r1 = f.y - __builtin_bit_cast(float, (u32)h1 << 16);
  float r2 = f.z - __builtin_bit_cast(float, (u32)h2 << 16);
  float r3 = f.w - __builtin_bit_cast(float, (u32)h3 << 16);
  hi = make_uint2((u32)h0 | ((u32)h1 << 16), (u32)h2 | ((u32)h3 << 16));
  lo = make_uint2((u32)f2bf(r0) | ((u32)f2bf(r1) << 16),
                  (u32)f2bf(r2) | ((u32)f2bf(r3) << 16));
}

// ---------------- kernel 1: CPB MLP -> bias_table[225][8] ----------------
__global__ void cpb_kernel(const float* __restrict__ w1, const float* __restrict__ b1,
                           const float* __restrict__ w2, float* __restrict__ bias_table) {
  __shared__ float hid[CPBH_];
  int p = blockIdx.x;        // 0..224
  int k = threadIdx.x;       // 0..511
  int hi = p / 15, wi = p % 15;
  float a0 = (float)(hi - 7) / 7.0f * 8.0f;
  float a1 = (float)(wi - 7) / 7.0f * 8.0f;
  float t0 = (a0 == 0.0f) ? 0.0f : copysignf(log2f(fabsf(a0) + 1.0f) / 3.0f, a0);
  float t1 = (a1 == 0.0f) ? 0.0f : copysignf(log2f(fabsf(a1) + 1.0f) / 3.0f, a1);
  float h = t0 * w1[2 * k] + t1 * w1[2 * k + 1] + b1[k];
  hid[k] = fmaxf(h, 0.0f);
  __syncthreads();
  if (k < NHD_) {
    float s = 0.0f;
    for (int j = 0; j < CPBH_; j++) s += hid[j] * w2[k * CPBH_ + j];
    bias_table[p * NHD_ + k] = s;
  }
}

// ---------------- kernel 2: gather + sigmoid -> rpb[8][64][64] ----------------
__global__ void rpb_kernel(const float* __restrict__ bias_table, float* __restrict__ rpb) {
  int h = blockIdx.x >> 6;   // grid 512
  int i = blockIdx.x & 63;
  int j = threadIdx.x;       // 64
  int dih = (i >> 3) - (j >> 3) + 7;
  int diw = (i & 7) - (j & 7) + 7;
  float v = bias_table[(dih * 15 + diw) * NHD_ + h];
  rpb[(((h << 6) + i) << 6) + j] = 16.0f / (1.0f + expf(-v));
}

// ---------------- weight fp32 -> bf16 conversion (single) ----------------
__global__ void convw_kernel(const float* __restrict__ w, u16* __restrict__ o, int n) {
  int i = blockIdx.x * 256 + threadIdx.x;
  if (i < n) o[i] = f2bf(w[i]);
}

// ---------------- weight fp32 -> bf16 hi/lo split ----------------
__global__ void convsplit_kernel(const float* __restrict__ w, u16* __restrict__ hi,
                                 u16* __restrict__ lo, int n) {
  int i = blockIdx.x * 256 + threadIdx.x;
  if (i < n) {
    float v = w[i];
    u16 h = f2bf(v);
    hi[i] = h;
    lo[i] = f2bf(v - __builtin_bit_cast(float, (u32)h << 16));
  }
}

// ---------------- kernel 3: shifted-window gather + QKV GEMM via split-bf16 MFMA ----------------
// One window (64 tokens) per block, 512 threads = 8 waves; wave w owns output cols [w*96, w*96+96).
// X staged in LDS as bf16 hi/lo with 16B-unit XOR swizzle (u ^= row&7) -> 64KB total, <=2-way banks.
__global__ __launch_bounds__(512) void qkv_mfma_kernel(
    const float* __restrict__ x,
    const u16* __restrict__ wh_, const u16* __restrict__ wl_,
    const float* __restrict__ qb, const float* __restrict__ vb,
    float* __restrict__ qo, float* __restrict__ ko, float* __restrict__ vo, int w0) {
  __shared__ u16 xh[64 * 256];
  __shared__ u16 xl[64 * 256];
  int tid = threadIdx.x;
  int lane = tid & 63, wid = tid >> 6;
  int lr = lane & 15, lk = lane >> 4;
  int wl2 = blockIdx.x;          // chunk-local window
  int w = w0 + wl2;
  int b = w >> 6, win = w & 63, wwh = win >> 3, www = win & 7;

#pragma unroll
  for (int i = 0; i < 8; i++) {
    int idx = tid + i * 512;     // float4 unit 0..4095
    int n = idx >> 6, c4 = idx & 63;
    int sh = wwh * 8 + (n >> 3), sw = www * 8 + (n & 7);
    int hh = (sh + SHIFT_) & 63, wc = (sw + SHIFT_) & 63;
    float4 f = *reinterpret_cast<const float4*>(
        x + ((size_t)((b << 12) + (hh << 6) + wc)) * CC_ + c4 * 4);
    uint2 hi, lo; split4(f, hi, lo);
    int u = c4 >> 1;             // 16B unit 0..31
    int off16 = n * 256 + ((u ^ (n & 7)) << 3) + ((c4 & 1) << 2);
    *reinterpret_cast<uint2*>(&xh[off16]) = hi;
    *reinterpret_cast<uint2*>(&xl[off16]) = lo;
  }
  __syncthreads();

  f32x4 acc[4][6];
#pragma unroll
  for (int m = 0; m < 4; m++)
#pragma unroll
    for (int nf = 0; nf < 6; nf++) acc[m][nf] = (f32x4){0.f, 0.f, 0.f, 0.f};

  for (int k0 = 0; k0 < CC_; k0 += 32) {
    int u0 = (k0 >> 3) + lk;
    bf16x8 ah[4], al[4];
#pragma unroll
    for (int m = 0; m < 4; m++) {
      int row = m * 16 + lr;
      int off16 = row * 256 + ((u0 ^ (row & 7)) << 3);
      ah[m] = *reinterpret_cast<const bf16x8*>(&xh[off16]);
      al[m] = *reinterpret_cast<const bf16x8*>(&xl[off16]);
    }
#pragma unroll
    for (int nf = 0; nf < 6; nf++) {
      int col = wid * 96 + nf * 16 + lr;
      size_t wo = (size_t)col * CC_ + k0 + lk * 8;
      bf16x8 bh = *reinterpret_cast<const bf16x8*>(wh_ + wo);
      bf16x8 bl = *reinterpret_cast<const bf16x8*>(wl_ + wo);
#pragma unroll
      for (int m = 0; m < 4; m++) {
        acc[m][nf] = __builtin_amdgcn_mfma_f32_16x16x32_bf16(ah[m], bh, acc[m][nf], 0, 0, 0);
        acc[m][nf] = __builtin_amdgcn_mfma_f32_16x16x32_bf16(al[m], bh, acc[m][nf], 0, 0, 0);
        acc[m][nf] = __builtin_amdgcn_mfma_f32_16x16x32_bf16(ah[m], bl, acc[m][nf], 0, 0, 0);
      }
    }
  }

#pragma unroll
  for (int nf = 0; nf < 6; nf++) {
    int col = wid * 96 + nf * 16 + lr;     // 16-col frag never straddles a 256 boundary
    int mat = col >> 8, cc = col & 255;
    float bias = (mat == 0) ? qb[cc] : ((mat == 2) ? vb[cc] : 0.f);
    float* dst = (mat == 0) ? qo : ((mat == 1) ? ko : vo);
    int hd = cc >> 5, d = cc & 31;
    float* dp = dst + ((size_t)(wl2 * NHD_ + hd) * NT_) * HD_ + d;
#pragma unroll
    for (int m = 0; m < 4; m++)
#pragma unroll
      for (int r = 0; r < 4; r++) {
        int n = m * 16 + lk * 4 + r;
        dp[(size_t)n * HD_] = acc[m][nf][r] + bias;
      }
  }
}

// ---------------- kernel 4: windowed cosine attention (chunk-local in and out) ----------------
__global__ __launch_bounds__(64) void attn_kernel(
    const float* __restrict__ qq, const float* __restrict__ kk_, const float* __restrict__ vv_,
    const float* __restrict__ ls, const float* __restrict__ rpb, float* __restrict__ attn_out, int w0) {
  __shared__ float ks[NT_][HD_];
  __shared__ float vs[NT_][HD_];
  int bid = blockIdx.x;          // nw*8 = wl*NH+h
  int wl = bid >> 3, h = bid & 7;
  int w = w0 + wl;               // global window
  int i = threadIdx.x;           // 64
  size_t base = (size_t)bid * (NT_ * HD_) + (size_t)i * HD_;  // chunk-local

  float qr[HD_];
  float ss = 0.f;
#pragma unroll
  for (int d = 0; d < HD_; d += 4) {
    float4 f = *reinterpret_cast<const float4*>(qq + base + d);
    qr[d] = f.x; qr[d + 1] = f.y; qr[d + 2] = f.z; qr[d + 3] = f.w;
    ss += f.x * f.x + f.y * f.y + f.z * f.z + f.w * f.w;
  }
  float inv = 1.0f / fmaxf(sqrtf(ss), 1e-12f);
#pragma unroll
  for (int d = 0; d < HD_; d++) qr[d] *= inv;

  float kr[HD_]; ss = 0.f;
#pragma unroll
  for (int d = 0; d < HD_; d += 4) {
    float4 f = *reinterpret_cast<const float4*>(kk_ + base + d);
    kr[d] = f.x; kr[d + 1] = f.y; kr[d + 2] = f.z; kr[d + 3] = f.w;
    ss += f.x * f.x + f.y * f.y + f.z * f.z + f.w * f.w;
  }
  inv = 1.0f / fmaxf(sqrtf(ss), 1e-12f);
#pragma unroll
  for (int d = 0; d < HD_; d += 4) {
    float4 t; t.x = kr[d] * inv; t.y = kr[d + 1] * inv; t.z = kr[d + 2] * inv; t.w = kr[d + 3] * inv;
    *reinterpret_cast<float4*>(&ks[i][d]) = t;
  }
#pragma unroll
  for (int d = 0; d < HD_; d += 4) {
    float4 f = *reinterpret_cast<const float4*>(vv_ + base + d);
    *reinterpret_cast<float4*>(&vs[i][d]) = f;
  }
  __syncthreads();

  float scale = expf(fminf(ls[h], 4.605170185988091f));  // clamp at log(100)
  const float* rp = rpb + (((h << 6) + i) << 6);
  int win = w & 63, wh = win >> 3, ww = win & 7;
  int regi = region9(wh * 8 + (i >> 3), ww * 8 + (i & 7));

  // pass 1: online max + denom
  float m = -1e30f, l = 0.f;
  for (int j = 0; j < NT_; j++) {
    float dot = dot32(qr, &ks[j][0]);
    int regj = region9(wh * 8 + (j >> 3), ww * 8 + (j & 7));
    float val = dot * scale + rp[j] + (regj == regi ? 0.f : -100.f);
    float nm = fmaxf(m, val);
    l = l * expf(m - nm) + expf(val - nm);
    m = nm;
  }
  float rl = 1.0f / l;

  // pass 2: recompute probs, accumulate P·V
  float acc[HD_];
#pragma unroll
  for (int d = 0; d < HD_; d++) acc[d] = 0.f;
  for (int j = 0; j < NT_; j++) {
    float dot = dot32(qr, &ks[j][0]);
    int regj = region9(wh * 8 + (j >> 3), ww * 8 + (j & 7));
    float val = dot * scale + rp[j] + (regj == regi ? 0.f : -100.f);
    float p = expf(val - m) * rl;
#pragma unroll
    for (int d = 0; d < HD_; d += 4) {
      float4 vvv = *reinterpret_cast<const float4*>(&vs[j][d]);
      acc[d] += p * vvv.x; acc[d + 1] += p * vvv.y; acc[d + 2] += p * vvv.z; acc[d + 3] += p * vvv.w;
    }
  }
  // chunk-local token index; layout [n, C] per window
  float* op = attn_out + ((size_t)(wl * NT_ + i)) * CC_ + h * HD_;
#pragma unroll
  for (int d = 0; d < HD_; d += 4) {
    float4 t; t.x = acc[d]; t.y = acc[d + 1]; t.z = acc[d + 2]; t.w = acc[d + 3];
    *reinterpret_cast<float4*>(op + d) = t;
  }
}

// ---------------- kernel 5: proj via split-bf16 MFMA + window-reverse + LN(norm1) + residual ----------------
// One window per block, 512 threads = 8 waves; wave w owns output cols [w*32, w*32+32).
__global__ __launch_bounds__(512) void proj_mfma_kernel(
    const float* __restrict__ attn_out,
    const u16* __restrict__ pwh, const u16* __restrict__ pwl, const float* __restrict__ pb,
    const float* __restrict__ g, const float* __restrict__ bb,
    const float* __restrict__ x, float* __restrict__ x1, int w0) {
  __shared__ union {
    struct { u16 ah[64 * 256]; u16 al[64 * 256]; } s;   // 64KB, live during GEMM
    float po[64][CC_];                                  // 64KB, live in epilogue
  } sm;
  int tid = threadIdx.x;
  int lane = tid & 63, wid = tid >> 6;
  int lr = lane & 15, lk = lane >> 4;
  int wl2 = blockIdx.x;
  int w = w0 + wl2;

#pragma unroll
  for (int i = 0; i < 8; i++) {
    int idx = tid + i * 512;
    int n = idx >> 6, c4 = idx & 63;
    float4 f = *reinterpret_cast<const float4*>(
        attn_out + ((size_t)(wl2 * NT_ + n)) * CC_ + c4 * 4);
    uint2 hi, lo; split4(f, hi, lo);
    int u = c4 >> 1;
    int off16 = n * 256 + ((u ^ (n & 7)) << 3) + ((c4 & 1) << 2);
    *reinterpret_cast<uint2*>(&sm.s.ah[off16]) = hi;
    *reinterpret_cast<uint2*>(&sm.s.al[off16]) = lo;
  }
  __syncthreads();

  f32x4 acc[4][2];
#pragma unroll
  for (int m = 0; m < 4; m++)
#pragma unroll
    for (int nf = 0; nf < 2; nf++) acc[m][nf] = (f32x4){0.f, 0.f, 0.f, 0.f};

  for (int k0 = 0; k0 < CC_; k0 += 32) {
    int u0 = (k0 >> 3) + lk;
    bf16x8 ah[4], al[4];
#pragma unroll
    for (int m = 0; m < 4; m++) {
      int row = m * 16 + lr;
      int off16 = row * 256 + ((u0 ^ (row & 7)) << 3);
      ah[m] = *reinterpret_cast<const bf16x8*>(&sm.s.ah[off16]);
      al[m] = *reinterpret_cast<const bf16x8*>(&sm.s.al[off16]);
    }
#pragma unroll
    for (int nf = 0; nf < 2; nf++) {
      int col = wid * 32 + nf * 16 + lr;
      size_t wo = (size_t)col * CC_ + k0 + lk * 8;
      bf16x8 bh = *reinterpret_cast<const bf16x8*>(pwh + wo);
      bf16x8 bl = *reinterpret_cast<const bf16x8*>(pwl + wo);
#pragma unroll
      for (int m = 0; m < 4; m++) {
        acc[m][nf] = __builtin_amdgcn_mfma_f32_16x16x32_bf16(ah[m], bh, acc[m][nf], 0, 0, 0);
        acc[m][nf] = __builtin_amdgcn_mfma_f32_16x16x32_bf16(al[m], bh, acc[m][nf], 0, 0, 0);
        acc[m][nf] = __builtin_amdgcn_mfma_f32_16x16x32_bf16(ah[m], bl, acc[m][nf], 0, 0, 0);
      }
    }
  }
  __syncthreads();   // staging dead; union becomes po

#pragma unroll
  for (int nf = 0; nf < 2; nf++) {
    int col = wid * 32 + nf * 16 + lr;
    float bv = pb[col];
#pragma unroll
    for (int m = 0; m < 4; m++)
#pragma unroll
      for (int r = 0; r < 4; r++)
        sm.po[m * 16 + lk * 4 + r][col] = acc[m][nf][r] + bv;
  }
  __syncthreads();

  // LN + window-reverse + residual; 8 lanes per token, token-rotated float4 slots
  int t = wid * 8 + (lane >> 3);
  int j8 = ((lane & 7) + (lane >> 3)) & 7;
  float4 pv[8];
  float sum = 0.f, sq = 0.f;
#pragma unroll
  for (int i = 0; i < 8; i++) {
    float4 v = *reinterpret_cast<const float4*>(&sm.po[t][j8 * 4 + i * 32]);
    pv[i] = v;
    sum += v.x + v.y + v.z + v.w;
    sq += v.x * v.x + v.y * v.y + v.z * v.z + v.w * v.w;
  }
#pragma unroll
  for (int off = 1; off < 8; off <<= 1) {
    sum += __shfl_xor(sum, off, 8);
    sq  += __shfl_xor(sq, off, 8);
  }
  float mean = sum * (1.0f / CC_);
  float var = sq * (1.0f / CC_) - mean * mean;
  float rs = rsqrtf(fmaxf(var, 0.0f) + 1e-5f);
  int b = w >> 6, win = w & 63, wwh = win >> 3, www = win & 7;
  int sh = wwh * 8 + (t >> 3), sw = www * 8 + (t & 7);
  int hh = (sh + SHIFT_) & 63, wc = (sw + SHIFT_) & 63;
  size_t tok = ((size_t)(b << 12)) + (hh << 6) + wc;
  const float* xrow = x + tok * CC_;
  float* orow = x1 + tok * CC_;
#pragma unroll
  for (int i = 0; i < 8; i++) {
    int c = j8 * 4 + i * 32;
    float4 xg = *reinterpret_cast<const float4*>(xrow + c);
    float4 gg = *reinterpret_cast<const float4*>(g + c);
    float4 bv = *reinterpret_cast<const float4*>(bb + c);
    float4 r;
    r.x = xg.x + (pv[i].x - mean) * rs * gg.x + bv.x;
    r.y = xg.y + (pv[i].y - mean) * rs * gg.y + bv.y;
    r.z = xg.z + (pv[i].z - mean) * rs * gg.z + bv.z;
    r.w = xg.w + (pv[i].w - mean) * rs * gg.w + bv.w;
    *reinterpret_cast<float4*>(orow + c) = r;
  }
}

// ---------------- kernel 6: MLP via bf16 MFMA (fc1+gelu+fc2) + LN(norm2) + residual ----------------
// 64 tokens/block, 512 threads = 8 waves. Hidden processed in 8 chunks of 128.
// fc1 computed with SWAPPED operands: D[hid][token] -> lane holds 4 consecutive hidden
// values -> packed ds_write_b64 into XOR-swizzled hid buffer. hid double-buffered ->
// 1 barrier per chunk. All LDS accesses <=2-way (16B-unit XOR swizzle, u ^= row&7).
#define BM_   64

__global__ __launch_bounds__(512) void mlp_mfma_kernel(
    const float* __restrict__ x1,
    const u16* __restrict__ w1bf, const float* __restrict__ b1,
    const u16* __restrict__ w2bf, const float* __restrict__ b2,
    const float* __restrict__ g, const float* __restrict__ bb,
    float* __restrict__ out) {
  __shared__ union {
    struct { u16 xs[64 * 256]; u16 hid[2][64 * 128]; } s;   // 32KB + 32KB
    float po[BM_][CC_];                                     // 64KB, epilogue only
  } sm;

  int tid = threadIdx.x;
  int lane = tid & 63;
  int wid = tid >> 6;        // 0..7
  int lr = lane & 15;
  int lk = lane >> 4;        // 0..3
  int whid = wid >> 1;       // fc1: hid rows [whid*32, +32)
  int wtok = wid & 1;        // fc1: tokens  [wtok*32, +32)
  int wout = wid >> 1;       // fc2: out cols [wout*64, +64)
  int wtk2 = wid & 1;        // fc2: tokens   [wtk2*32, +32)
  size_t t0 = (size_t)blockIdx.x * BM_;

  // ---- stage x1 tile -> bf16 swizzled LDS ----
#pragma unroll
  for (int i = 0; i < 8; i++) {
    int idx = tid + i * 512;          // float4 index, 0..4095
    int row = idx >> 6;
    int c4 = idx & 63;
    float4 f = *reinterpret_cast<const float4*>(x1 + (t0 + row) * CC_ + c4 * 4);
    u32 p0 = (u32)f2bf(f.x) | ((u32)f2bf(f.y) << 16);
    u32 p1 = (u32)f2bf(f.z) | ((u32)f2bf(f.w) << 16);
    int u = c4 >> 1;
    int off16 = row * 256 + ((u ^ (row & 7)) << 3) + ((c4 & 1) << 2);
    *reinterpret_cast<uint2*>(&sm.s.xs[off16]) = make_uint2(p0, p1);
  }

  f32x4 acc2[2][4];
#pragma unroll
  for (int mf = 0; mf < 2; mf++)
#pragma unroll
    for (int nf = 0; nf < 4; nf++) acc2[mf][nf] = (f32x4){0.f, 0.f, 0.f, 0.f};

  // fc1 for chunk ch: D[hid][token] via mfma(w1_frag, x_frag); gelu; pack -> hid[ch&1]
  auto FC1 = [&](int ch) {
    int h0 = ch * 128;
    f32x4 acc1[2][2];   // [hf hid frag][tf token frag]
#pragma unroll
    for (int hf = 0; hf < 2; hf++)
#pragma unroll
      for (int tf = 0; tf < 2; tf++) acc1[hf][tf] = (f32x4){0.f, 0.f, 0.f, 0.f};
#pragma unroll
    for (int k0 = 0; k0 < CC_; k0 += 32) {
      bf16x8 a0 = *reinterpret_cast<const bf16x8*>(
          w1bf + (size_t)(h0 + whid * 32 + lr) * CC_ + k0 + lk * 8);
      bf16x8 a1 = *reinterpret_cast<const bf16x8*>(
          w1bf + (size_t)(h0 + whid * 32 + 16 + lr) * CC_ + k0 + lk * 8);
      int u0 = (k0 >> 3) + lk;
      int r0 = wtok * 32 + lr;
      int r1 = wtok * 32 + 16 + lr;
      bf16x8 bx0 = *reinterpret_cast<const bf16x8*>(&sm.s.xs[r0 * 256 + ((u0 ^ (r0 & 7)) << 3)]);
      bf16x8 bx1 = *reinterpret_cast<const bf16x8*>(&sm.s.xs[r1 * 256 + ((u0 ^ (r1 & 7)) << 3)]);
      acc1[0][0] = __builtin_amdgcn_mfma_f32_16x16x32_bf16(a0, bx0, acc1[0][0], 0, 0, 0);
      acc1[0][1] = __builtin_amdgcn_mfma_f32_16x16x32_bf16(a0, bx1, acc1[0][1], 0, 0, 0);
      acc1[1][0] = __builtin_amdgcn_mfma_f32_16x16x32_bf16(a1, bx0, acc1[1][0], 0, 0, 0);
      acc1[1][1] = __builtin_amdgcn_mfma_f32_16x16x32_bf16(a1, bx1, acc1[1][1], 0, 0, 0);
    }
    u16* hb = &sm.s.hid[ch & 1][0];
#pragma unroll
    for (int hf = 0; hf < 2; hf++) {
      float4 bq = *reinterpret_cast<const float4*>(b1 + h0 + whid * 32 + hf * 16 + lk * 4);
      int col = whid * 32 + hf * 16 + lk * 4;      // 0..124, step 4
      int u = col >> 3;                            // 16B unit 0..15
      int half4 = (lk & 1) << 2;                   // 8B half within unit
#pragma unroll
      for (int tf = 0; tf < 2; tf++) {
        int token = wtok * 32 + tf * 16 + lr;
        float v0 = acc1[hf][tf][0] + bq.x;
        float v1 = acc1[hf][tf][1] + bq.y;
        float v2 = acc1[hf][tf][2] + bq.z;
        float v3 = acc1[hf][tf][3] + bq.w;
        v0 = 0.5f * v0 * (1.0f + erff(v0 * 0.7071067811865475f));
        v1 = 0.5f * v1 * (1.0f + erff(v1 * 0.7071067811865475f));
        v2 = 0.5f * v2 * (1.0f + erff(v2 * 0.7071067811865475f));
        v3 = 0.5f * v3 * (1.0f + erff(v3 * 0.7071067811865475f));
        u32 p0 = (u32)f2bf(v0) | ((u32)f2bf(v1) << 16);
        u32 p1 = (u32)f2bf(v2) | ((u32)f2bf(v3) << 16);
        int off16 = token * 128 + ((u ^ (token & 7)) << 3) + half4;
        *reinterpret_cast<uint2*>(&hb[off16]) = make_uint2(p0, p1);
      }
    }
  };

  // fc2 partial for chunk ch: accumulate D[token][outcol] from hid[ch&1]
  auto FC2 = [&](int ch) {
    int h0 = ch * 128;
    const u16* hb = &sm.s.hid[ch & 1][0];
#pragma unroll
    for (int kk = 0; kk < 128; kk += 32) {
      int u0 = (kk >> 3) + lk;    // unit 0..15
      int r0 = wtk2 * 32 + lr;
      int r1 = wtk2 * 32 + 16 + lr;
      bf16x8 a0 = *reinterpret_cast<const bf16x8*>(&hb[r0 * 128 + ((u0 ^ (r0 & 7)) << 3)]);
      bf16x8 a1 = *reinterpret_cast<const bf16x8*>(&hb[r1 * 128 + ((u0 ^ (r1 & 7)) << 3)]);
#pragma unroll
      for (int nf = 0; nf < 4; nf++) {
        bf16x8 bf = *reinterpret_cast<const bf16x8*>(
            w2bf + (size_t)(wout * 64 + nf * 16 + lr) * HID_ + h0 + kk + lk * 8);
        acc2[0][nf] = __builtin_amdgcn_mfma_f32_16x16x32_bf16(a0, bf, acc2[0][nf], 0, 0, 0);
        acc2[1][nf] = __builtin_amdgcn_mfma_f32_16x16x32_bf16(a1, bf, acc2[1][nf], 0, 0, 0);
      }
    }
  };

  __syncthreads();          // xs staged
  FC1(0);
  __syncthreads();          // hid[0] ready
  for (int ch = 0; ch < 8; ch++) {
    if (ch < 7) FC1(ch + 1);   // writes hid[(ch+1)&1]; last reader finished before prev barrier
    FC2(ch);                   // reads hid[ch&1]
    __syncthreads();
  }
  // union becomes po

  // ---- write fc2 result + bias to po ----
#pragma unroll
  for (int mf = 0; mf < 2; mf++)
#pragma unroll
    for (int nf = 0; nf < 4; nf++) {
      int col = wout * 64 + nf * 16 + lr;
      float bv = b2[col];
#pragma unroll
      for (int r = 0; r < 4; r++) {
        int row = wtk2 * 32 + mf * 16 + lk * 4 + r;
        sm.po[row][col] = acc2[mf][nf][r] + bv;
      }
    }
  __syncthreads();

  // ---- LN(norm2) + residual; 8 lanes per token, token-rotated float4 slots ----
  int t = wid * 8 + (lane >> 3);
  int j8 = ((lane & 7) + (lane >> 3)) & 7;
  float4 pv[8];
  float sum = 0.f, sq = 0.f;
#pragma unroll
  for (int i = 0; i < 8; i++) {
    float4 v = *reinterpret_cast<const float4*>(&sm.po[t][j8 * 4 + i * 32]);
    pv[i] = v;
    sum += v.x + v.y + v.z + v.w;
    sq += v.x * v.x + v.y * v.y + v.z * v.z + v.w * v.w;
  }
#pragma unroll
  for (int off = 1; off < 8; off <<= 1) {
    sum += __shfl_xor(sum, off, 8);
    sq  += __shfl_xor(sq, off, 8);
  }
  float mean = sum * (1.0f / CC_);
  float var = sq * (1.0f / CC_) - mean * mean;
  float rs = rsqrtf(fmaxf(var, 0.0f) + 1e-5f);
  const float* xrow = x1 + (t0 + t) * CC_;
  float* orow = out + (t0 + t) * CC_;
#pragma unroll
  for (int i = 0; i < 8; i++) {
    int c = j8 * 4 + i * 32;
    float4 xg = *reinterpret_cast<const float4*>(xrow + c);
    float4 gg = *reinterpret_cast<const float4*>(g + c);
    float4 bv = *reinterpret_cast<const float4*>(bb + c);
    float4 r;
    r.x = xg.x + (pv[i].x - mean) * rs * gg.x + bv.x;
    r.y = xg.y + (pv[i].y - mean) * rs * gg.y + bv.y;
    r.z = xg.z + (pv[i].z - mean) * rs * gg.z + bv.z;
    r.w = xg.w + (pv[i].w - mean) * rs * gg.w + bv.w;
    *reinterpret_cast<float4*>(orow + c) = r;
  }
}

extern "C" void kernel_launch(void* const* d_in, const int* in_sizes, int n_in,
                              void* d_out, int out_size, void* d_ws, size_t ws_size,
                              hipStream_t stream) {
  const float* x       = (const float*)d_in[0];
  const float* qkv_w   = (const float*)d_in[1];
  const float* q_bias  = (const float*)d_in[2];
  const float* v_bias  = (const float*)d_in[3];
  const float* logit_s = (const float*)d_in[4];
  const float* cpb_w1  = (const float*)d_in[5];
  const float* cpb_b1  = (const float*)d_in[6];
  const float* cpb_w2  = (const float*)d_in[7];
  const float* proj_w  = (const float*)d_in[8];
  const float* proj_b  = (const float*)d_in[9];
  const float* n1g     = (const float*)d_in[10];
  const float* n1b     = (const float*)d_in[11];
  const float* n2g     = (const float*)d_in[12];
  const float* n2b     = (const float*)d_in[13];
  const float* fc1_w   = (const float*)d_in[14];
  const float* fc1_b   = (const float*)d_in[15];
  const float* fc2_w   = (const float*)d_in[16];
  const float* fc2_b   = (const float*)d_in[17];
  float* out = (float*)d_out;
  char* ws = (char*)d_ws;

  // Workspace layout:
  //   [0,      8192): bias_table
  //   [8192, 139264): rpb (8*64*64 fp32)
  //   [139264, 663552):  fc1_w bf16
  //   [663552, 1187840): fc2_w bf16
  //   [1187840, 1581056): qkv_w bf16 hi (768*256*2)
  //   [1581056, 1974272): qkv_w bf16 lo
  //   [1974272, 2105344): proj_w bf16 hi (256*256*2)
  //   [2105344, 2236416): proj_w bf16 lo
  //   [2236416, ...):  per-chunk q,k,v,attn_out (fp32), nc windows each
  u16* fc1bf = (u16*)(ws + 139264);
  u16* fc2bf = (u16*)(ws + 663552);
  u16* qwh   = (u16*)(ws + 1187840);
  u16* qwl   = (u16*)(ws + 1581056);
  u16* pwh   = (u16*)(ws + 1974272);
  u16* pwl   = (u16*)(ws + 2105344);
  const size_t OFF_CH = 2236416;
  const size_t ELEM_PER_WIN = (size_t)NHD_ * NT_ * HD_;      // 16384 fp32 elems per buffer per window
  const size_t PER_WIN_BYTES = 4 * ELEM_PER_WIN * 4;         // q+k+v+attn = 262144 B/window

  float* bias_table = (float*)(ws);
  float* rpb        = (float*)(ws + 8192);

  long long avail = (long long)ws_size - (long long)OFF_CH;
  long long ncw = avail / (long long)PER_WIN_BYTES;
  if (ncw < 1) ncw = 1;
  if (ncw > BW_) ncw = BW_;
  int nc = (int)ncw;   // windows per chunk — depends only on ws_size (graph-safe)

  float* qc = (float*)(ws + OFF_CH);
  float* kc = qc + (size_t)nc * ELEM_PER_WIN;
  float* vc = kc + (size_t)nc * ELEM_PER_WIN;
  float* ac = vc + (size_t)nc * ELEM_PER_WIN;

  cpb_kernel<<<225, 512, 0, stream>>>(cpb_w1, cpb_b1, cpb_w2, bias_table);
  rpb_kernel<<<NHD_ * NT_, 64, 0, stream>>>(bias_table, rpb);
  convw_kernel<<<1024, 256, 0, stream>>>(fc1_w, fc1bf, HID_ * CC_);
  convw_kernel<<<1024, 256, 0, stream>>>(fc2_w, fc2bf, CC_ * HID_);
  convsplit_kernel<<<768, 256, 0, stream>>>(qkv_w, qwh, qwl, 3 * CC_ * CC_);
  convsplit_kernel<<<256, 256, 0, stream>>>(proj_w, pwh, pwl, CC_ * CC_);

  for (int w0 = 0; w0 < BW_; w0 += nc) {
    int nw = (BW_ - w0 < nc) ? (BW_ - w0) : nc;
    qkv_mfma_kernel<<<nw, 512, 0, stream>>>(x, qwh, qwl, q_bias, v_bias, qc, kc, vc, w0);
    attn_kernel<<<nw * 8, 64, 0, stream>>>(qc, kc, vc, logit_s, rpb, ac, w0);
    proj_mfma_kernel<<<nw, 512, 0, stream>>>(ac, pwh, pwl, proj_b, n1g, n1b, x, out, w0);
  }
  mlp_mfma_kernel<<<TOK_ / BM_, 512, 0, stream>>>(out, fc1bf, fc1_b, fc2bf, fc2_b, n2g, n2b, out);
}

// Round 5
// 1645.731 us; speedup vs baseline: 5.2623x; 1.0168x over previous
//
#include <hip/hip_runtime.h>

typedef unsigned short u16;
typedef unsigned int u32;
typedef __attribute__((ext_vector_type(8))) short bf16x8;
typedef __attribute__((ext_vector_type(4))) float f32x4;

#define CC_    256         // channels
#define NHD_   8           // heads
#define NT_    64          // tokens per window
#define HD_    32          // head dim
#define HID_   1024        // mlp hidden
#define CPBH_  512         // cpb hidden
#define BW_    2048        // total windows = 32 * 64
#define TOK_   131072      // total tokens
#define SHIFT_ 4

// region id (0..8) in the shifted canvas for mask construction
__device__ __forceinline__ int region9(int ph, int pw) {
  return (ph < 56 ? 0 : (ph < 60 ? 3 : 6)) + (pw < 56 ? 0 : (pw < 60 ? 1 : 2));
}
__device__ __forceinline__ float dot32(const float* qr, const float* krow) {
  float d0 = 0.f, d1 = 0.f, d2 = 0.f, d3 = 0.f;
#pragma unroll
  for (int d = 0; d < HD_; d += 4) {
    float4 kk = *reinterpret_cast<const float4*>(krow + d);
    d0 += qr[d] * kk.x; d1 += qr[d + 1] * kk.y;
    d2 += qr[d + 2] * kk.z; d3 += qr[d + 3] * kk.w;
  }
  return (d0 + d1) + (d2 + d3);
}

// fp32 -> bf16 round-to-nearest-even (finite values only)
__device__ __forceinline__ u16 f2bf(float f) {
  u32 u = __builtin_bit_cast(u32, f);
  u = (u + 0x7FFFu + ((u >> 16) & 1u)) >> 16;
  return (u16)u;
}

// split a float4 into bf16 hi + bf16 lo (x ~= hi + lo, rel err ~2^-16)
__device__ __forceinline__ void split4(float4 f, uint2& hi, uint2& lo) {
  u16 h0 = f2bf(f.x), h1 = f2bf(f.y), h2 = f2bf(f.z), h3 = f2bf(f.w);
  float r0 = f.x - __builtin_bit_cast(float, (u32)h0 << 16);
  float r1 = f.y - __builtin_bit_cast(float, (u32)h1 << 16);
  float r2 = f.z - __builtin_bit_cast(float, (u32)h2 << 16);
  float r3 = f.w - __builtin_bit_cast(float, (u32)h3 << 16);
  hi = make_uint2((u32)h0 | ((u32)h1 << 16), (u32)h2 | ((u32)h3 << 16));
  lo = make_uint2((u32)f2bf(r0) | ((u32)f2bf(r1) << 16),
                  (u32)f2bf(r2) | ((u32)f2bf(r3) << 16));
}

// ---------------- kernel 1: CPB MLP -> bias_table[225][8] ----------------
__global__ void cpb_kernel(const float* __restrict__ w1, const float* __restrict__ b1,
                           const float* __restrict__ w2, float* __restrict__ bias_table) {
  __shared__ float hid[CPBH_];
  int p = blockIdx.x;        // 0..224
  int k = threadIdx.x;       // 0..511
  int hi = p / 15, wi = p % 15;
  float a0 = (float)(hi - 7) / 7.0f * 8.0f;
  float a1 = (float)(wi - 7) / 7.0f * 8.0f;
  float t0 = (a0 == 0.0f) ? 0.0f : copysignf(log2f(fabsf(a0) + 1.0f) / 3.0f, a0);
  float t1 = (a1 == 0.0f) ? 0.0f : copysignf(log2f(fabsf(a1) + 1.0f) / 3.0f, a1);
  float h = t0 * w1[2 * k] + t1 * w1[2 * k + 1] + b1[k];
  hid[k] = fmaxf(h, 0.0f);
  __syncthreads();
  if (k < NHD_) {
    float s = 0.0f;
    for (int j = 0; j < CPBH_; j++) s += hid[j] * w2[k * CPBH_ + j];
    bias_table[p * NHD_ + k] = s;
  }
}

// ---------------- kernel 2: gather + sigmoid -> rpbT[8][64(j)][64(i)] (TRANSPOSED) ----------------
// Stored as [h][j][i] so attn's per-j read of all i is coalesced.
__global__ void rpb_kernel(const float* __restrict__ bias_table, float* __restrict__ rpb) {
  int h = blockIdx.x >> 6;   // grid 512
  int j = blockIdx.x & 63;
  int i = threadIdx.x;       // 64
  int dih = (i >> 3) - (j >> 3) + 7;
  int diw = (i & 7) - (j & 7) + 7;
  float v = bias_table[(dih * 15 + diw) * NHD_ + h];
  rpb[(((h << 6) + j) << 6) + i] = 16.0f / (1.0f + expf(-v));
}

// ---------------- weight fp32 -> bf16 conversion (single) ----------------
__global__ void convw_kernel(const float* __restrict__ w, u16* __restrict__ o, int n) {
  int i = blockIdx.x * 256 + threadIdx.x;
  if (i < n) o[i] = f2bf(w[i]);
}

// ---------------- weight fp32 -> bf16 hi/lo split ----------------
__global__ void convsplit_kernel(const float* __restrict__ w, u16* __restrict__ hi,
                                 u16* __restrict__ lo, int n) {
  int i = blockIdx.x * 256 + threadIdx.x;
  if (i < n) {
    float v = w[i];
    u16 h = f2bf(v);
    hi[i] = h;
    lo[i] = f2bf(v - __builtin_bit_cast(float, (u32)h << 16));
  }
}

// ---------------- kernel 3: shifted-window gather + QKV GEMM via split-bf16 MFMA ----------------
// One window (64 tokens) per block, 512 threads = 8 waves; wave w owns output cols [w*96, w*96+96).
// X staged in LDS as bf16 hi/lo with 16B-unit XOR swizzle (u ^= row&7) -> 64KB total, <=2-way banks.
__global__ __launch_bounds__(512) void qkv_mfma_kernel(
    const float* __restrict__ x,
    const u16* __restrict__ wh_, const u16* __restrict__ wl_,
    const float* __restrict__ qb, const float* __restrict__ vb,
    float* __restrict__ qo, float* __restrict__ ko, float* __restrict__ vo, int w0) {
  __shared__ u16 xh[64 * 256];
  __shared__ u16 xl[64 * 256];
  int tid = threadIdx.x;
  int lane = tid & 63, wid = tid >> 6;
  int lr = lane & 15, lk = lane >> 4;
  int wl2 = blockIdx.x;          // chunk-local window
  int w = w0 + wl2;
  int b = w >> 6, win = w & 63, wwh = win >> 3, www = win & 7;

#pragma unroll
  for (int i = 0; i < 8; i++) {
    int idx = tid + i * 512;     // float4 unit 0..4095
    int n = idx >> 6, c4 = idx & 63;
    int sh = wwh * 8 + (n >> 3), sw = www * 8 + (n & 7);
    int hh = (sh + SHIFT_) & 63, wc = (sw + SHIFT_) & 63;
    float4 f = *reinterpret_cast<const float4*>(
        x + ((size_t)((b << 12) + (hh << 6) + wc)) * CC_ + c4 * 4);
    uint2 hi, lo; split4(f, hi, lo);
    int u = c4 >> 1;             // 16B unit 0..31
    int off16 = n * 256 + ((u ^ (n & 7)) << 3) + ((c4 & 1) << 2);
    *reinterpret_cast<uint2*>(&xh[off16]) = hi;
    *reinterpret_cast<uint2*>(&xl[off16]) = lo;
  }
  __syncthreads();

  f32x4 acc[4][6];
#pragma unroll
  for (int m = 0; m < 4; m++)
#pragma unroll
    for (int nf = 0; nf < 6; nf++) acc[m][nf] = (f32x4){0.f, 0.f, 0.f, 0.f};

  for (int k0 = 0; k0 < CC_; k0 += 32) {
    int u0 = (k0 >> 3) + lk;
    bf16x8 ah[4], al[4];
#pragma unroll
    for (int m = 0; m < 4; m++) {
      int row = m * 16 + lr;
      int off16 = row * 256 + ((u0 ^ (row & 7)) << 3);
      ah[m] = *reinterpret_cast<const bf16x8*>(&xh[off16]);
      al[m] = *reinterpret_cast<const bf16x8*>(&xl[off16]);
    }
#pragma unroll
    for (int nf = 0; nf < 6; nf++) {
      int col = wid * 96 + nf * 16 + lr;
      size_t wo = (size_t)col * CC_ + k0 + lk * 8;
      bf16x8 bh = *reinterpret_cast<const bf16x8*>(wh_ + wo);
      bf16x8 bl = *reinterpret_cast<const bf16x8*>(wl_ + wo);
#pragma unroll
      for (int m = 0; m < 4; m++) {
        acc[m][nf] = __builtin_amdgcn_mfma_f32_16x16x32_bf16(ah[m], bh, acc[m][nf], 0, 0, 0);
        acc[m][nf] = __builtin_amdgcn_mfma_f32_16x16x32_bf16(al[m], bh, acc[m][nf], 0, 0, 0);
        acc[m][nf] = __builtin_amdgcn_mfma_f32_16x16x32_bf16(ah[m], bl, acc[m][nf], 0, 0, 0);
      }
    }
  }

#pragma unroll
  for (int nf = 0; nf < 6; nf++) {
    int col = wid * 96 + nf * 16 + lr;     // 16-col frag never straddles a 256 boundary
    int mat = col >> 8, cc = col & 255;
    float bias = (mat == 0) ? qb[cc] : ((mat == 2) ? vb[cc] : 0.f);
    float* dst = (mat == 0) ? qo : ((mat == 1) ? ko : vo);
    int hd = cc >> 5, d = cc & 31;
    float* dp = dst + ((size_t)(wl2 * NHD_ + hd) * NT_) * HD_ + d;
#pragma unroll
    for (int m = 0; m < 4; m++)
#pragma unroll
      for (int r = 0; r < 4; r++) {
        int n = m * 16 + lk * 4 + r;
        dp[(size_t)n * HD_] = acc[m][nf][r] + bias;
      }
  }
}

// ---------------- kernel 4: windowed cosine attention, SINGLE-PASS softmax ----------------
// Shift-invariant softmax with static shift M = scale + 16 (val <= scale*1 + rpb_max(16) + 0 = M;
// diagonal guarantees l >= exp(-16), so no underflow for any logit_scale).
__global__ __launch_bounds__(64) void attn_kernel(
    const float* __restrict__ qq, const float* __restrict__ kk_, const float* __restrict__ vv_,
    const float* __restrict__ ls, const float* __restrict__ rpbT, float* __restrict__ attn_out, int w0) {
  __shared__ float ks[NT_][HD_];
  __shared__ float vs[NT_][HD_];
  int bid = blockIdx.x;          // nw*8 = wl*NH+h
  int wl = bid >> 3, h = bid & 7;
  int w = w0 + wl;               // global window
  int i = threadIdx.x;           // 64
  size_t base = (size_t)bid * (NT_ * HD_) + (size_t)i * HD_;  // chunk-local

  float qr[HD_];
  float ss = 0.f;
#pragma unroll
  for (int d = 0; d < HD_; d += 4) {
    float4 f = *reinterpret_cast<const float4*>(qq + base + d);
    qr[d] = f.x; qr[d + 1] = f.y; qr[d + 2] = f.z; qr[d + 3] = f.w;
    ss += f.x * f.x + f.y * f.y + f.z * f.z + f.w * f.w;
  }
  float inv = 1.0f / fmaxf(sqrtf(ss), 1e-12f);
#pragma unroll
  for (int d = 0; d < HD_; d++) qr[d] *= inv;

  float kr[HD_]; ss = 0.f;
#pragma unroll
  for (int d = 0; d < HD_; d += 4) {
    float4 f = *reinterpret_cast<const float4*>(kk_ + base + d);
    kr[d] = f.x; kr[d + 1] = f.y; kr[d + 2] = f.z; kr[d + 3] = f.w;
    ss += f.x * f.x + f.y * f.y + f.z * f.z + f.w * f.w;
  }
  inv = 1.0f / fmaxf(sqrtf(ss), 1e-12f);
#pragma unroll
  for (int d = 0; d < HD_; d += 4) {
    float4 t; t.x = kr[d] * inv; t.y = kr[d + 1] * inv; t.z = kr[d + 2] * inv; t.w = kr[d + 3] * inv;
    *reinterpret_cast<float4*>(&ks[i][d]) = t;
  }
#pragma unroll
  for (int d = 0; d < HD_; d += 4) {
    float4 f = *reinterpret_cast<const float4*>(vv_ + base + d);
    *reinterpret_cast<float4*>(&vs[i][d]) = f;
  }
  __syncthreads();

  float scale = expf(fminf(ls[h], 4.605170185988091f));  // clamp at log(100)
  float M = scale + 16.0f;
  const float* rpT = rpbT + ((h << 6) << 6) + i;   // rpbT[h][j][i], coalesced over i
  int win = w & 63, wh = win >> 3, ww = win & 7;
  int regi = region9(wh * 8 + (i >> 3), ww * 8 + (i & 7));

  float l = 0.f;
  float acc[HD_];
#pragma unroll
  for (int d = 0; d < HD_; d++) acc[d] = 0.f;
  for (int j = 0; j < NT_; j++) {
    float dot = dot32(qr, &ks[j][0]);
    int regj = region9(wh * 8 + (j >> 3), ww * 8 + (j & 7));
    float val = dot * scale + rpT[j << 6] + (regj == regi ? 0.f : -100.f);
    float p = expf(val - M);
    l += p;
#pragma unroll
    for (int d = 0; d < HD_; d += 4) {
      float4 vvv = *reinterpret_cast<const float4*>(&vs[j][d]);
      acc[d] += p * vvv.x; acc[d + 1] += p * vvv.y; acc[d + 2] += p * vvv.z; acc[d + 3] += p * vvv.w;
    }
  }
  float rl = 1.0f / l;

  // chunk-local token index; layout [n, C] per window
  float* op = attn_out + ((size_t)(wl * NT_ + i)) * CC_ + h * HD_;
#pragma unroll
  for (int d = 0; d < HD_; d += 4) {
    float4 t; t.x = acc[d] * rl; t.y = acc[d + 1] * rl; t.z = acc[d + 2] * rl; t.w = acc[d + 3] * rl;
    *reinterpret_cast<float4*>(op + d) = t;
  }
}

// ---------------- kernel 5: proj via split-bf16 MFMA + window-reverse + LN(norm1) + residual ----------------
// One window per block, 512 threads = 8 waves; wave w owns output cols [w*32, w*32+32).
__global__ __launch_bounds__(512) void proj_mfma_kernel(
    const float* __restrict__ attn_out,
    const u16* __restrict__ pwh, const u16* __restrict__ pwl, const float* __restrict__ pb,
    const float* __restrict__ g, const float* __restrict__ bb,
    const float* __restrict__ x, float* __restrict__ x1, int w0) {
  __shared__ union {
    struct { u16 ah[64 * 256]; u16 al[64 * 256]; } s;   // 64KB, live during GEMM
    float po[64][CC_];                                  // 64KB, live in epilogue
  } sm;
  int tid = threadIdx.x;
  int lane = tid & 63, wid = tid >> 6;
  int lr = lane & 15, lk = lane >> 4;
  int wl2 = blockIdx.x;
  int w = w0 + wl2;

#pragma unroll
  for (int i = 0; i < 8; i++) {
    int idx = tid + i * 512;
    int n = idx >> 6, c4 = idx & 63;
    float4 f = *reinterpret_cast<const float4*>(
        attn_out + ((size_t)(wl2 * NT_ + n)) * CC_ + c4 * 4);
    uint2 hi, lo; split4(f, hi, lo);
    int u = c4 >> 1;
    int off16 = n * 256 + ((u ^ (n & 7)) << 3) + ((c4 & 1) << 2);
    *reinterpret_cast<uint2*>(&sm.s.ah[off16]) = hi;
    *reinterpret_cast<uint2*>(&sm.s.al[off16]) = lo;
  }
  __syncthreads();

  f32x4 acc[4][2];
#pragma unroll
  for (int m = 0; m < 4; m++)
#pragma unroll
    for (int nf = 0; nf < 2; nf++) acc[m][nf] = (f32x4){0.f, 0.f, 0.f, 0.f};

  for (int k0 = 0; k0 < CC_; k0 += 32) {
    int u0 = (k0 >> 3) + lk;
    bf16x8 ah[4], al[4];
#pragma unroll
    for (int m = 0; m < 4; m++) {
      int row = m * 16 + lr;
      int off16 = row * 256 + ((u0 ^ (row & 7)) << 3);
      ah[m] = *reinterpret_cast<const bf16x8*>(&sm.s.ah[off16]);
      al[m] = *reinterpret_cast<const bf16x8*>(&sm.s.al[off16]);
    }
#pragma unroll
    for (int nf = 0; nf < 2; nf++) {
      int col = wid * 32 + nf * 16 + lr;
      size_t wo = (size_t)col * CC_ + k0 + lk * 8;
      bf16x8 bh = *reinterpret_cast<const bf16x8*>(pwh + wo);
      bf16x8 bl = *reinterpret_cast<const bf16x8*>(pwl + wo);
#pragma unroll
      for (int m = 0; m < 4; m++) {
        acc[m][nf] = __builtin_amdgcn_mfma_f32_16x16x32_bf16(ah[m], bh, acc[m][nf], 0, 0, 0);
        acc[m][nf] = __builtin_amdgcn_mfma_f32_16x16x32_bf16(al[m], bh, acc[m][nf], 0, 0, 0);
        acc[m][nf] = __builtin_amdgcn_mfma_f32_16x16x32_bf16(ah[m], bl, acc[m][nf], 0, 0, 0);
      }
    }
  }
  __syncthreads();   // staging dead; union becomes po

#pragma unroll
  for (int nf = 0; nf < 2; nf++) {
    int col = wid * 32 + nf * 16 + lr;
    float bv = pb[col];
#pragma unroll
    for (int m = 0; m < 4; m++)
#pragma unroll
      for (int r = 0; r < 4; r++)
        sm.po[m * 16 + lk * 4 + r][col] = acc[m][nf][r] + bv;
  }
  __syncthreads();

  // LN + window-reverse + residual; 8 lanes per token, token-rotated float4 slots
  int t = wid * 8 + (lane >> 3);
  int j8 = ((lane & 7) + (lane >> 3)) & 7;
  float4 pv[8];
  float sum = 0.f, sq = 0.f;
#pragma unroll
  for (int i = 0; i < 8; i++) {
    float4 v = *reinterpret_cast<const float4*>(&sm.po[t][j8 * 4 + i * 32]);
    pv[i] = v;
    sum += v.x + v.y + v.z + v.w;
    sq += v.x * v.x + v.y * v.y + v.z * v.z + v.w * v.w;
  }
#pragma unroll
  for (int off = 1; off < 8; off <<= 1) {
    sum += __shfl_xor(sum, off, 8);
    sq  += __shfl_xor(sq, off, 8);
  }
  float mean = sum * (1.0f / CC_);
  float var = sq * (1.0f / CC_) - mean * mean;
  float rs = rsqrtf(fmaxf(var, 0.0f) + 1e-5f);
  int b = w >> 6, win = w & 63, wwh = win >> 3, www = win & 7;
  int sh = wwh * 8 + (t >> 3), sw = www * 8 + (t & 7);
  int hh = (sh + SHIFT_) & 63, wc = (sw + SHIFT_) & 63;
  size_t tok = ((size_t)(b << 12)) + (hh << 6) + wc;
  const float* xrow = x + tok * CC_;
  float* orow = x1 + tok * CC_;
#pragma unroll
  for (int i = 0; i < 8; i++) {
    int c = j8 * 4 + i * 32;
    float4 xg = *reinterpret_cast<const float4*>(xrow + c);
    float4 gg = *reinterpret_cast<const float4*>(g + c);
    float4 bv = *reinterpret_cast<const float4*>(bb + c);
    float4 r;
    r.x = xg.x + (pv[i].x - mean) * rs * gg.x + bv.x;
    r.y = xg.y + (pv[i].y - mean) * rs * gg.y + bv.y;
    r.z = xg.z + (pv[i].z - mean) * rs * gg.z + bv.z;
    r.w = xg.w + (pv[i].w - mean) * rs * gg.w + bv.w;
    *reinterpret_cast<float4*>(orow + c) = r;
  }
}

// ---------------- kernel 6: MLP via bf16 MFMA (fc1+gelu+fc2) + LN(norm2) + residual ----------------
// 64 tokens/block, 512 threads = 8 waves. Hidden in 8 chunks of 128, hid double-buffered.
// NEW: the x-side fragments (bx) are hoisted into registers once (they are chunk-invariant),
// removing the 8x-redundant fc1 LDS reads; fc1 inner loop is global-weight + MFMA only.
#define BM_   64

__global__ __launch_bounds__(512) void mlp_mfma_kernel(
    const float* __restrict__ x1,
    const u16* __restrict__ w1bf, const float* __restrict__ b1,
    const u16* __restrict__ w2bf, const float* __restrict__ b2,
    const float* __restrict__ g, const float* __restrict__ bb,
    float* __restrict__ out) {
  __shared__ union {
    struct { u16 xs[64 * 256]; u16 hid[2][64 * 128]; } s;   // 32KB + 32KB
    float po[BM_][CC_];                                     // 64KB, epilogue only
  } sm;

  int tid = threadIdx.x;
  int lane = tid & 63;
  int wid = tid >> 6;        // 0..7
  int lr = lane & 15;
  int lk = lane >> 4;        // 0..3
  int whid = wid >> 1;       // fc1: hid rows [whid*32, +32)
  int wtok = wid & 1;        // fc1: tokens  [wtok*32, +32)
  int wout = wid >> 1;       // fc2: out cols [wout*64, +64)
  int wtk2 = wid & 1;        // fc2: tokens   [wtk2*32, +32)
  size_t t0 = (size_t)blockIdx.x * BM_;

  // ---- stage x1 tile -> bf16 swizzled LDS ----
#pragma unroll
  for (int i = 0; i < 8; i++) {
    int idx = tid + i * 512;          // float4 index, 0..4095
    int row = idx >> 6;
    int c4 = idx & 63;
    float4 f = *reinterpret_cast<const float4*>(x1 + (t0 + row) * CC_ + c4 * 4);
    u32 p0 = (u32)f2bf(f.x) | ((u32)f2bf(f.y) << 16);
    u32 p1 = (u32)f2bf(f.z) | ((u32)f2bf(f.w) << 16);
    int u = c4 >> 1;
    int off16 = row * 256 + ((u ^ (row & 7)) << 3) + ((c4 & 1) << 2);
    *reinterpret_cast<uint2*>(&sm.s.xs[off16]) = make_uint2(p0, p1);
  }

  f32x4 acc2[2][4];
#pragma unroll
  for (int mf = 0; mf < 2; mf++)
#pragma unroll
    for (int nf = 0; nf < 4; nf++) acc2[mf][nf] = (f32x4){0.f, 0.f, 0.f, 0.f};

  __syncthreads();          // xs staged

  // ---- hoist x-fragments to registers (chunk-invariant): 16 x bf16x8 = 64 VGPR ----
  bf16x8 bx[8][2];
#pragma unroll
  for (int k0i = 0; k0i < 8; k0i++) {
    int u0 = k0i * 4 + lk;
#pragma unroll
    for (int tf = 0; tf < 2; tf++) {
      int rr = wtok * 32 + tf * 16 + lr;
      bx[k0i][tf] = *reinterpret_cast<const bf16x8*>(&sm.s.xs[rr * 256 + ((u0 ^ (rr & 7)) << 3)]);
    }
  }

  // fc1 for chunk ch: D[hid][token] via mfma(w1_frag, x_frag); gelu; pack -> hid[ch&1]
  auto FC1 = [&](int ch) {
    int h0 = ch * 128;
    f32x4 acc1[2][2];   // [hf hid frag][tf token frag]
#pragma unroll
    for (int hf = 0; hf < 2; hf++)
#pragma unroll
      for (int tf = 0; tf < 2; tf++) acc1[hf][tf] = (f32x4){0.f, 0.f, 0.f, 0.f};
#pragma unroll
    for (int k0i = 0; k0i < 8; k0i++) {
      int k0 = k0i * 32;
      bf16x8 a0 = *reinterpret_cast<const bf16x8*>(
          w1bf + (size_t)(h0 + whid * 32 + lr) * CC_ + k0 + lk * 8);
      bf16x8 a1 = *reinterpret_cast<const bf16x8*>(
          w1bf + (size_t)(h0 + whid * 32 + 16 + lr) * CC_ + k0 + lk * 8);
      acc1[0][0] = __builtin_amdgcn_mfma_f32_16x16x32_bf16(a0, bx[k0i][0], acc1[0][0], 0, 0, 0);
      acc1[0][1] = __builtin_amdgcn_mfma_f32_16x16x32_bf16(a0, bx[k0i][1], acc1[0][1], 0, 0, 0);
      acc1[1][0] = __builtin_amdgcn_mfma_f32_16x16x32_bf16(a1, bx[k0i][0], acc1[1][0], 0, 0, 0);
      acc1[1][1] = __builtin_amdgcn_mfma_f32_16x16x32_bf16(a1, bx[k0i][1], acc1[1][1], 0, 0, 0);
    }
    u16* hb = &sm.s.hid[ch & 1][0];
#pragma unroll
    for (int hf = 0; hf < 2; hf++) {
      float4 bq = *reinterpret_cast<const float4*>(b1 + h0 + whid * 32 + hf * 16 + lk * 4);
      int col = whid * 32 + hf * 16 + lk * 4;      // 0..124, step 4
      int u = col >> 3;                            // 16B unit 0..15
      int half4 = (lk & 1) << 2;                   // 8B half within unit
#pragma unroll
      for (int tf = 0; tf < 2; tf++) {
        int token = wtok * 32 + tf * 16 + lr;
        float v0 = acc1[hf][tf][0] + bq.x;
        float v1 = acc1[hf][tf][1] + bq.y;
        float v2 = acc1[hf][tf][2] + bq.z;
        float v3 = acc1[hf][tf][3] + bq.w;
        v0 = 0.5f * v0 * (1.0f + erff(v0 * 0.7071067811865475f));
        v1 = 0.5f * v1 * (1.0f + erff(v1 * 0.7071067811865475f));
        v2 = 0.5f * v2 * (1.0f + erff(v2 * 0.7071067811865475f));
        v3 = 0.5f * v3 * (1.0f + erff(v3 * 0.7071067811865475f));
        u32 p0 = (u32)f2bf(v0) | ((u32)f2bf(v1) << 16);
        u32 p1 = (u32)f2bf(v2) | ((u32)f2bf(v3) << 16);
        int off16 = token * 128 + ((u ^ (token & 7)) << 3) + half4;
        *reinterpret_cast<uint2*>(&hb[off16]) = make_uint2(p0, p1);
      }
    }
  };

  // fc2 partial for chunk ch: accumulate D[token][outcol] from hid[ch&1]
  auto FC2 = [&](int ch) {
    int h0 = ch * 128;
    const u16* hb = &sm.s.hid[ch & 1][0];
#pragma unroll
    for (int kk = 0; kk < 128; kk += 32) {
      int u0 = (kk >> 3) + lk;    // unit 0..15
      int r0 = wtk2 * 32 + lr;
      int r1 = wtk2 * 32 + 16 + lr;
      bf16x8 a0 = *reinterpret_cast<const bf16x8*>(&hb[r0 * 128 + ((u0 ^ (r0 & 7)) << 3)]);
      bf16x8 a1 = *reinterpret_cast<const bf16x8*>(&hb[r1 * 128 + ((u0 ^ (r1 & 7)) << 3)]);
#pragma unroll
      for (int nf = 0; nf < 4; nf++) {
        bf16x8 bf = *reinterpret_cast<const bf16x8*>(
            w2bf + (size_t)(wout * 64 + nf * 16 + lr) * HID_ + h0 + kk + lk * 8);
        acc2[0][nf] = __builtin_amdgcn_mfma_f32_16x16x32_bf16(a0, bf, acc2[0][nf], 0, 0, 0);
        acc2[1][nf] = __builtin_amdgcn_mfma_f32_16x16x32_bf16(a1, bf, acc2[1][nf], 0, 0, 0);
      }
    }
  };

  FC1(0);
  __syncthreads();          // hid[0] ready
  for (int ch = 0; ch < 8; ch++) {
    if (ch < 7) FC1(ch + 1);   // writes hid[(ch+1)&1]; last reader finished before prev barrier
    FC2(ch);                   // reads hid[ch&1]
    __syncthreads();
  }
  // union becomes po

  // ---- write fc2 result + bias to po ----
#pragma unroll
  for (int mf = 0; mf < 2; mf++)
#pragma unroll
    for (int nf = 0; nf < 4; nf++) {
      int col = wout * 64 + nf * 16 + lr;
      float bv = b2[col];
#pragma unroll
      for (int r = 0; r < 4; r++) {
        int row = wtk2 * 32 + mf * 16 + lk * 4 + r;
        sm.po[row][col] = acc2[mf][nf][r] + bv;
      }
    }
  __syncthreads();

  // ---- LN(norm2) + residual; 8 lanes per token, token-rotated float4 slots ----
  int t = wid * 8 + (lane >> 3);
  int j8 = ((lane & 7) + (lane >> 3)) & 7;
  float4 pv[8];
  float sum = 0.f, sq = 0.f;
#pragma unroll
  for (int i = 0; i < 8; i++) {
    float4 v = *reinterpret_cast<const float4*>(&sm.po[t][j8 * 4 + i * 32]);
    pv[i] = v;
    sum += v.x + v.y + v.z + v.w;
    sq += v.x * v.x + v.y * v.y + v.z * v.z + v.w * v.w;
  }
#pragma unroll
  for (int off = 1; off < 8; off <<= 1) {
    sum += __shfl_xor(sum, off, 8);
    sq  += __shfl_xor(sq, off, 8);
  }
  float mean = sum * (1.0f / CC_);
  float var = sq * (1.0f / CC_) - mean * mean;
  float rs = rsqrtf(fmaxf(var, 0.0f) + 1e-5f);
  const float* xrow = x1 + (t0 + t) * CC_;
  float* orow = out + (t0 + t) * CC_;
#pragma unroll
  for (int i = 0; i < 8; i++) {
    int c = j8 * 4 + i * 32;
    float4 xg = *reinterpret_cast<const float4*>(xrow + c);
    float4 gg = *reinterpret_cast<const float4*>(g + c);
    float4 bv = *reinterpret_cast<const float4*>(bb + c);
    float4 r;
    r.x = xg.x + (pv[i].x - mean) * rs * gg.x + bv.x;
    r.y = xg.y + (pv[i].y - mean) * rs * gg.y + bv.y;
    r.z = xg.z + (pv[i].z - mean) * rs * gg.z + bv.z;
    r.w = xg.w + (pv[i].w - mean) * rs * gg.w + bv.w;
    *reinterpret_cast<float4*>(orow + c) = r;
  }
}

extern "C" void kernel_launch(void* const* d_in, const int* in_sizes, int n_in,
                              void* d_out, int out_size, void* d_ws, size_t ws_size,
                              hipStream_t stream) {
  const float* x       = (const float*)d_in[0];
  const float* qkv_w   = (const float*)d_in[1];
  const float* q_bias  = (const float*)d_in[2];
  const float* v_bias  = (const float*)d_in[3];
  const float* logit_s = (const float*)d_in[4];
  const float* cpb_w1  = (const float*)d_in[5];
  const float* cpb_b1  = (const float*)d_in[6];
  const float* cpb_w2  = (const float*)d_in[7];
  const float* proj_w  = (const float*)d_in[8];
  const float* proj_b  = (const float*)d_in[9];
  const float* n1g     = (const float*)d_in[10];
  const float* n1b     = (const float*)d_in[11];
  const float* n2g     = (const float*)d_in[12];
  const float* n2b     = (const float*)d_in[13];
  const float* fc1_w   = (const float*)d_in[14];
  const float* fc1_b   = (const float*)d_in[15];
  const float* fc2_w   = (const float*)d_in[16];
  const float* fc2_b   = (const float*)d_in[17];
  float* out = (float*)d_out;
  char* ws = (char*)d_ws;

  // Workspace layout:
  //   [0,      8192): bias_table
  //   [8192, 139264): rpbT (8*64*64 fp32, [h][j][i])
  //   [139264, 663552):  fc1_w bf16
  //   [663552, 1187840): fc2_w bf16
  //   [1187840, 1581056): qkv_w bf16 hi (768*256*2)
  //   [1581056, 1974272): qkv_w bf16 lo
  //   [1974272, 2105344): proj_w bf16 hi (256*256*2)
  //   [2105344, 2236416): proj_w bf16 lo
  //   [2236416, ...):  per-chunk q,k,v,attn_out (fp32), nc windows each
  u16* fc1bf = (u16*)(ws + 139264);
  u16* fc2bf = (u16*)(ws + 663552);
  u16* qwh   = (u16*)(ws + 1187840);
  u16* qwl   = (u16*)(ws + 1581056);
  u16* pwh   = (u16*)(ws + 1974272);
  u16* pwl   = (u16*)(ws + 2105344);
  const size_t OFF_CH = 2236416;
  const size_t ELEM_PER_WIN = (size_t)NHD_ * NT_ * HD_;      // 16384 fp32 elems per buffer per window
  const size_t PER_WIN_BYTES = 4 * ELEM_PER_WIN * 4;         // q+k+v+attn = 262144 B/window

  float* bias_table = (float*)(ws);
  float* rpb        = (float*)(ws + 8192);

  long long avail = (long long)ws_size - (long long)OFF_CH;
  long long ncw = avail / (long long)PER_WIN_BYTES;
  if (ncw < 1) ncw = 1;
  if (ncw > BW_) ncw = BW_;
  int nc = (int)ncw;   // windows per chunk — depends only on ws_size (graph-safe)

  float* qc = (float*)(ws + OFF_CH);
  float* kc = qc + (size_t)nc * ELEM_PER_WIN;
  float* vc = kc + (size_t)nc * ELEM_PER_WIN;
  float* ac = vc + (size_t)nc * ELEM_PER_WIN;

  cpb_kernel<<<225, 512, 0, stream>>>(cpb_w1, cpb_b1, cpb_w2, bias_table);
  rpb_kernel<<<NHD_ * NT_, 64, 0, stream>>>(bias_table, rpb);
  convw_kernel<<<1024, 256, 0, stream>>>(fc1_w, fc1bf, HID_ * CC_);
  convw_kernel<<<1024, 256, 0, stream>>>(fc2_w, fc2bf, CC_ * HID_);
  convsplit_kernel<<<768, 256, 0, stream>>>(qkv_w, qwh, qwl, 3 * CC_ * CC_);
  convsplit_kernel<<<256, 256, 0, stream>>>(proj_w, pwh, pwl, CC_ * CC_);

  for (int w0 = 0; w0 < BW_; w0 += nc) {
    int nw = (BW_ - w0 < nc) ? (BW_ - w0) : nc;
    qkv_mfma_kernel<<<nw, 512, 0, stream>>>(x, qwh, qwl, q_bias, v_bias, qc, kc, vc, w0);
    attn_kernel<<<nw * 8, 64, 0, stream>>>(qc, kc, vc, logit_s, rpb, ac, w0);
    proj_mfma_kernel<<<nw, 512, 0, stream>>>(ac, pwh, pwl, proj_b, n1g, n1b, x, out, w0);
  }
  mlp_mfma_kernel<<<TOK_ / BM_, 512, 0, stream>>>(out, fc1bf, fc1_b, fc2bf, fc2_b, n2g, n2b, out);
}